// Round 3
// baseline (8928.373 us; speedup 1.0000x reference)
//
#include <hip/hip_runtime.h>
#include <math.h>

#define NA 131072   // atoms
#define NE 262144   // edges
#define NG 4096     // graphs
#define FN 30
#define FE 11
#define H  256
#define H2 512
#define NL 5
#define BN_EPS 1e-5f

// ---- private fallback workspace, allocated ONCE at library load (outside
// any graph capture; kernel_launch itself stays malloc-free & deterministic).
static float* g_buf = nullptr;
__attribute__((constructor)) static void _alloc_private_ws() {
    void* p = nullptr;
    // h (128 MiB) + z (128 MiB) + z1 (256 MiB) + 1 MiB slack
    if (hipMalloc(&p, (size_t)513 * 1024 * 1024) == hipSuccess) g_buf = (float*)p;
}

// ---------------- encoders ----------------
__global__ __launch_bounds__(H) void encode_nodes(const float* __restrict__ x,
                                                  const float* __restrict__ w,
                                                  const float* __restrict__ b,
                                                  float* __restrict__ h) {
    __shared__ float xs[FN];
    const int row = blockIdx.x;
    const int c = threadIdx.x;
    if (c < FN) xs[c] = x[(size_t)row * FN + c];
    __syncthreads();
    float acc = b[c];
    #pragma unroll
    for (int k = 0; k < FN; ++k) acc += xs[k] * w[k * H + c];
    h[(size_t)row * H + c] = acc;
}

// ---------------- z = (1+eps_l) * h ----------------
__global__ __launch_bounds__(256) void scale_h(const float* __restrict__ h,
                                               const float* __restrict__ eps, int l,
                                               float* __restrict__ z) {
    const size_t i = (size_t)blockIdx.x * blockDim.x + threadIdx.x;
    const float s = 1.0f + eps[l];
    float4 v = ((const float4*)h)[i];
    v.x *= s; v.y *= s; v.z *= s; v.w *= s;
    ((float4*)z)[i] = v;
}

// ---- message + scatter-add with fused bond encoder:
//      z[dst] += relu(h[src] + edge_attr@bond_w + bond_b)
// 4 edges per 256-thread block; 64 lanes per edge; 4 consecutive cols per lane.
__global__ __launch_bounds__(256) void message_agg(const float* __restrict__ h,
                                                   const float* __restrict__ eattr,
                                                   const float* __restrict__ bond_w,
                                                   const float* __restrict__ bond_b,
                                                   const int* __restrict__ ei,
                                                   float* __restrict__ z) {
    const int eb = threadIdx.x >> 6;     // edge slot in block: 0..3
    const int lane = threadIdx.x & 63;
    const int edge = blockIdx.x * 4 + eb;
    __shared__ float ea_s[4][FE];
    if (lane < FE) ea_s[eb][lane] = eattr[(size_t)edge * FE + lane];
    __syncthreads();
    const int src = ei[edge];
    const int dst = ei[NE + edge];
    const int c = lane * 4;
    float4 v = *(const float4*)(h + (size_t)src * H + c);
    float4 ev = *(const float4*)(bond_b + c);
    #pragma unroll
    for (int k = 0; k < FE; ++k) {
        const float a = ea_s[eb][k];
        const float4 w = *(const float4*)(bond_w + (size_t)k * H + c);
        ev.x += a * w.x; ev.y += a * w.y; ev.z += a * w.z; ev.w += a * w.w;
    }
    float* zp = z + (size_t)dst * H + c;
    atomicAdd(zp + 0, fmaxf(v.x + ev.x, 0.0f));
    atomicAdd(zp + 1, fmaxf(v.y + ev.y, 0.0f));
    atomicAdd(zp + 2, fmaxf(v.z + ev.z, 0.0f));
    atomicAdd(zp + 3, fmaxf(v.w + ev.w, 0.0f));
}

// ---------------- tiled fp32 GEMM with fused BN(+bias)+relu (+residual) ----------------
// C[M,Ncols] = epilogue(A[M,K] @ B[K,Ncols]); BM=128, BN=64, BK=16, 256 threads,
// each thread owns an 8x4 micro-tile.
template <int EPI>  // 0: relu(bn(acc+bias))   1: relu(bn(acc+bias)) + res (res may alias C)
__global__ __launch_bounds__(256) void gemm_bn(const float* __restrict__ A,
                                               const float* __restrict__ B,
                                               int K, int Ncols,
                                               const float* __restrict__ bias,
                                               const float* __restrict__ bng,
                                               const float* __restrict__ bnb,
                                               const float* __restrict__ bnm,
                                               const float* __restrict__ bnv,
                                               float* __restrict__ C,
                                               const float* __restrict__ res) {
    __shared__ float As[16][128];
    __shared__ float Bs[16][64];
    const int tid = threadIdx.x;
    const int tm = tid >> 4;         // 0..15 -> rows tm*8..tm*8+7
    const int tn = tid & 15;         // 0..15 -> cols tn*4..tn*4+3
    const int m0 = blockIdx.y * 128;
    const int n0 = blockIdx.x * 64;

    const int lr = tid >> 2;         // 0..63  (A loader rows lr, lr+64)
    const int lk = (tid & 3) * 4;    // 0,4,8,12
    const int kb = tid >> 4;         // 0..15  (B loader row)
    const int nq = (tid & 15) * 4;   // 0..60  (B loader col quad)

    const float* Arow0 = A + (size_t)(m0 + lr) * K + lk;
    const float* Arow1 = A + (size_t)(m0 + lr + 64) * K + lk;
    const float* Bptr  = B + (size_t)kb * Ncols + n0 + nq;

    float acc[8][4];
    #pragma unroll
    for (int i = 0; i < 8; ++i)
        #pragma unroll
        for (int j = 0; j < 4; ++j) acc[i][j] = 0.0f;

    for (int k0 = 0; k0 < K; k0 += 16) {
        const float4 a0 = *(const float4*)(Arow0 + k0);
        const float4 a1 = *(const float4*)(Arow1 + k0);
        const float4 b0 = *(const float4*)(Bptr + (size_t)k0 * Ncols);
        __syncthreads();   // previous iteration's LDS reads complete
        As[lk + 0][lr] = a0.x;  As[lk + 1][lr] = a0.y;
        As[lk + 2][lr] = a0.z;  As[lk + 3][lr] = a0.w;
        As[lk + 0][lr + 64] = a1.x;  As[lk + 1][lr + 64] = a1.y;
        As[lk + 2][lr + 64] = a1.z;  As[lk + 3][lr + 64] = a1.w;
        *(float4*)&Bs[kb][nq] = b0;
        __syncthreads();
        #pragma unroll
        for (int kk = 0; kk < 16; ++kk) {
            const float4 av0 = *(const float4*)&As[kk][tm * 8];
            const float4 av1 = *(const float4*)&As[kk][tm * 8 + 4];
            const float4 bv  = *(const float4*)&Bs[kk][tn * 4];
            const float a_[8] = {av0.x, av0.y, av0.z, av0.w, av1.x, av1.y, av1.z, av1.w};
            const float b_[4] = {bv.x, bv.y, bv.z, bv.w};
            #pragma unroll
            for (int i = 0; i < 8; ++i)
                #pragma unroll
                for (int j = 0; j < 4; ++j) acc[i][j] += a_[i] * b_[j];
        }
    }

    float scale[4], shift[4];
    #pragma unroll
    for (int j = 0; j < 4; ++j) {
        const int c = n0 + tn * 4 + j;
        const float s = bng[c] * rsqrtf(bnv[c] + BN_EPS);
        scale[j] = s;
        shift[j] = s * (bias[c] - bnm[c]) + bnb[c];
    }
    #pragma unroll
    for (int i = 0; i < 8; ++i) {
        const size_t off = (size_t)(m0 + tm * 8 + i) * Ncols + n0 + tn * 4;
        float4 rv = make_float4(0.f, 0.f, 0.f, 0.f);
        if (EPI == 1) rv = *(const float4*)(res + off);
        float4 o;
        o.x = fmaxf(scale[0] * acc[i][0] + shift[0], 0.f) + rv.x;
        o.y = fmaxf(scale[1] * acc[i][1] + shift[1], 0.f) + rv.y;
        o.z = fmaxf(scale[2] * acc[i][2] + shift[2], 0.f) + rv.z;
        o.w = fmaxf(scale[3] * acc[i][3] + shift[3], 0.f) + rv.w;
        *(float4*)(C + off) = o;
    }
}

// ---------------- pooling: mean + max per graph ----------------
__global__ __launch_bounds__(H) void pool_kernel(const float* __restrict__ h,
                                                 const int* __restrict__ batch,
                                                 float* __restrict__ p) {
    const int g = blockIdx.x;
    const int c = threadIdx.x;
    int lo, hi;
    {
        int a = 0, b = NA;
        while (a < b) { int mid = (a + b) >> 1; if (batch[mid] < g) a = mid + 1; else b = mid; }
        lo = a;
        b = NA;
        while (a < b) { int mid = (a + b) >> 1; if (batch[mid] < g + 1) a = mid + 1; else b = mid; }
        hi = a;
    }
    float sum = 0.0f, mx = -INFINITY;
    for (int n = lo; n < hi; ++n) {
        const float v = h[(size_t)n * H + c];
        sum += v;
        mx = fmaxf(mx, v);
    }
    const int cnt = hi - lo;
    const float mean = (cnt > 0) ? sum / (float)cnt : 0.0f;
    if (cnt == 0) mx = 0.0f;
    p[(size_t)g * H2 + c] = mean;
    p[(size_t)g * H2 + H + c] = mx;
}

// ---------------- classifier row-MLP: out = relu(bn(A@W + bias)) ----------------
template <int Kdim, int Ncols>
__global__ __launch_bounds__(Ncols) void rowmlp(const float* __restrict__ A,
                                                const float* __restrict__ W,
                                                const float* __restrict__ bias,
                                                const float* __restrict__ bg,
                                                const float* __restrict__ bb,
                                                const float* __restrict__ bm,
                                                const float* __restrict__ bv,
                                                float* __restrict__ out) {
    __shared__ float as[Kdim];
    const int row = blockIdx.x;
    const int c = threadIdx.x;
    for (int k = c; k < Kdim; k += Ncols) as[k] = A[(size_t)row * Kdim + k];
    __syncthreads();
    float acc = 0.0f;
    #pragma unroll 8
    for (int k = 0; k < Kdim; ++k) acc += as[k] * W[k * Ncols + c];
    const float s = bg[c] * rsqrtf(bv[c] + BN_EPS);
    const float val = s * (acc + bias[c] - bm[c]) + bb[c];
    out[(size_t)row * Ncols + c] = fmaxf(val, 0.0f);
}

__global__ __launch_bounds__(64) void final_out(const float* __restrict__ q2,
                                                const float* __restrict__ w,
                                                const float* __restrict__ b,
                                                float* __restrict__ out) {
    const int g = blockIdx.x;
    const int lane = threadIdx.x;
    float acc = q2[(size_t)g * 128 + lane] * w[lane]
              + q2[(size_t)g * 128 + 64 + lane] * w[64 + lane];
    #pragma unroll
    for (int off = 32; off > 0; off >>= 1) acc += __shfl_down(acc, off);
    if (lane == 0) out[g] = acc + b[0];
}

// ---------------- launch ----------------
extern "C" void kernel_launch(void* const* d_in, const int* in_sizes, int n_in,
                              void* d_out, int out_size, void* d_ws, size_t ws_size,
                              hipStream_t stream) {
    const float* x      = (const float*)d_in[0];
    const int*   ei     = (const int*)d_in[1];
    const int*   batch  = (const int*)d_in[2];
    const float* eattr  = (const float*)d_in[3];
    const float* enc_w  = (const float*)d_in[4];
    const float* enc_b  = (const float*)d_in[5];
    const float* bond_w = (const float*)d_in[6];
    const float* bond_b = (const float*)d_in[7];
    const float* eps    = (const float*)d_in[8];
    const float* w1     = (const float*)d_in[9];
    const float* b1     = (const float*)d_in[10];
    const float* ibn_g  = (const float*)d_in[11];
    const float* ibn_b  = (const float*)d_in[12];
    const float* ibn_m  = (const float*)d_in[13];
    const float* ibn_v  = (const float*)d_in[14];
    const float* w2     = (const float*)d_in[15];
    const float* b2     = (const float*)d_in[16];
    const float* obn_g  = (const float*)d_in[17];
    const float* obn_b  = (const float*)d_in[18];
    const float* obn_m  = (const float*)d_in[19];
    const float* obn_v  = (const float*)d_in[20];
    const float* cw1    = (const float*)d_in[21];
    const float* cb1    = (const float*)d_in[22];
    const float* c1g    = (const float*)d_in[23];
    const float* c1b    = (const float*)d_in[24];
    const float* c1m    = (const float*)d_in[25];
    const float* c1v    = (const float*)d_in[26];
    const float* cw2    = (const float*)d_in[27];
    const float* cb2    = (const float*)d_in[28];
    const float* c2g    = (const float*)d_in[29];
    const float* c2b    = (const float*)d_in[30];
    const float* c2m    = (const float*)d_in[31];
    const float* c2v    = (const float*)d_in[32];
    const float* cw3    = (const float*)d_in[33];
    const float* cb3    = (const float*)d_in[34];
    float* out = (float*)d_out;

    // ---- workspace selection (deterministic: ws_size & g_buf fixed per run) ----
    // Full layout: [h: NA*H][z: NA*H][z1: NA*H2]  = 512 MiB (fp32)
    const size_t need_full = ((size_t)NA * H * 2 + (size_t)NA * H2) * sizeof(float);
    float* buf;
    size_t buf_bytes;
    if (ws_size >= need_full) { buf = (float*)d_ws; buf_bytes = ws_size; }
    else if (g_buf)           { buf = g_buf;        buf_bytes = need_full; }
    else                      { buf = (float*)d_ws; buf_bytes = ws_size; }

    float* h   = buf;
    float* z   = h + (size_t)NA * H;
    float* z1c = z + (size_t)NA * H;

    const size_t base_f  = (size_t)NA * H * 2;
    const size_t avail_f = (buf_bytes / 4 > base_f) ? buf_bytes / 4 - base_f : 0;
    int CH = (int)(avail_f / H2);
    CH &= ~127;                       // multiple of 128 rows
    if (CH > NA) CH = NA;
    if (CH < 128) CH = 128;           // floor (only insufficient if both ws paths tiny)

    float* p  = z;                    // NG*H2   (z dead after last layer)
    float* q1 = p + (size_t)NG * H2;  // NG*H
    float* q2 = q1 + (size_t)NG * H;  // NG*(H/2)

    encode_nodes<<<NA, H, 0, stream>>>(x, enc_w, enc_b, h);

    for (int l = 0; l < NL; ++l) {
        scale_h<<<(NA * H / 4) / 256, 256, 0, stream>>>(h, eps, l, z);
        message_agg<<<NE / 4, 256, 0, stream>>>(h, eattr, bond_w, bond_b, ei, z);
        for (int r0 = 0; r0 < NA; r0 += CH) {
            const int CHc = (NA - r0 < CH) ? (NA - r0) : CH;
            dim3 g1(H2 / 64, CHc / 128);
            gemm_bn<0><<<g1, 256, 0, stream>>>(z + (size_t)r0 * H,
                                               w1 + (size_t)l * H * H2, H, H2,
                                               b1 + (size_t)l * H2, ibn_g + (size_t)l * H2,
                                               ibn_b + (size_t)l * H2, ibn_m + (size_t)l * H2,
                                               ibn_v + (size_t)l * H2, z1c, nullptr);
            dim3 g2(H / 64, CHc / 128);
            gemm_bn<1><<<g2, 256, 0, stream>>>(z1c, w2 + (size_t)l * H2 * H, H2, H,
                                               b2 + (size_t)l * H, obn_g + (size_t)l * H,
                                               obn_b + (size_t)l * H, obn_m + (size_t)l * H,
                                               obn_v + (size_t)l * H,
                                               h + (size_t)r0 * H, h + (size_t)r0 * H);
        }
    }

    pool_kernel<<<NG, H, 0, stream>>>(h, batch, p);
    rowmlp<H2, H><<<NG, H, 0, stream>>>(p, cw1, cb1, c1g, c1b, c1m, c1v, q1);
    rowmlp<H, H / 2><<<NG, H / 2, 0, stream>>>(q1, cw2, cb2, c2g, c2b, c2m, c2v, q2);
    final_out<<<NG, 64, 0, stream>>>(q2, cw3, cb3, out);
}

// Round 4
// 5502.116 us; speedup vs baseline: 1.6227x; 1.6227x over previous
//
#include <hip/hip_runtime.h>
#include <math.h>

#define NA 131072   // atoms
#define NE 262144   // edges
#define NG 4096     // graphs
#define FN 30
#define FE 11
#define H  256
#define H2 512
#define NL 5
#define BN_EPS 1e-5f

// CSR int region: deg/cursor reuse + rowptr + elist, padded to 64-word align
#define CSR_WORDS (3 * NA + NE + 64)   // deg(NA) + rowptr(NA+1) + cursor(NA) + elist(NE), padded

// ---- private fallback workspace, allocated ONCE at library load (outside
// any graph capture; kernel_launch itself stays malloc-free & deterministic).
static float* g_buf = nullptr;
__attribute__((constructor)) static void _alloc_private_ws() {
    void* p = nullptr;
    // csr(2.7 MiB) + h(128) + z(128) + z1(256) + slack
    if (hipMalloc(&p, (size_t)536 * 1024 * 1024) == hipSuccess) g_buf = (float*)p;
}

// ---------------- node encoder ----------------
__global__ __launch_bounds__(H) void encode_nodes(const float* __restrict__ x,
                                                  const float* __restrict__ w,
                                                  const float* __restrict__ b,
                                                  float* __restrict__ h) {
    __shared__ float xs[FN];
    const int row = blockIdx.x;
    const int c = threadIdx.x;
    if (c < FN) xs[c] = x[(size_t)row * FN + c];
    __syncthreads();
    float acc = b[c];
    #pragma unroll
    for (int k = 0; k < FN; ++k) acc += xs[k] * w[k * H + c];
    h[(size_t)row * H + c] = acc;
}

// ---------------- CSR build (once per call) ----------------
__global__ __launch_bounds__(256) void count_deg(const int* __restrict__ ei,
                                                 int* __restrict__ deg) {
    const int e = blockIdx.x * 256 + threadIdx.x;
    if (e < NE) atomicAdd(&deg[ei[NE + e]], 1);
}

__global__ __launch_bounds__(1024) void scan_deg(const int* __restrict__ deg,
                                                 int* __restrict__ rowptr,
                                                 int* __restrict__ cursor) {
    __shared__ int part[1024];
    const int t = threadIdx.x;
    const int base = t * 128;               // 1024*128 == NA
    int s = 0;
    #pragma unroll 8
    for (int i = 0; i < 128; ++i) s += deg[base + i];
    part[t] = s;
    __syncthreads();
    for (int off = 1; off < 1024; off <<= 1) {
        const int v = (t >= off) ? part[t - off] : 0;
        __syncthreads();
        part[t] += v;
        __syncthreads();
    }
    int run = (t == 0) ? 0 : part[t - 1];
    #pragma unroll 8
    for (int i = 0; i < 128; ++i) {
        rowptr[base + i] = run;
        cursor[base + i] = run;
        run += deg[base + i];
    }
    if (t == 1023) rowptr[NA] = run;        // == NE
}

__global__ __launch_bounds__(256) void fill_elist(const int* __restrict__ ei,
                                                  int* __restrict__ cursor,
                                                  int* __restrict__ elist) {
    const int e = blockIdx.x * 256 + threadIdx.x;
    if (e < NE) {
        const int pos = atomicAdd(&cursor[ei[NE + e]], 1);
        elist[pos] = e;
    }
}

// ---- GINE aggregation (gather form, fuses (1+eps)*h and bond encoder):
//      z[dst] = (1+eps)*h[dst] + sum_e relu(h[src_e] + eattr_e @ bond_w + bond_b)
// one block per dst node, one thread per column.
__global__ __launch_bounds__(H) void gine_msg(const float* __restrict__ h,
                                              const float* __restrict__ eattr,
                                              const float* __restrict__ bond_w,
                                              const float* __restrict__ bond_b,
                                              const int* __restrict__ ei,
                                              const int* __restrict__ rowptr,
                                              const int* __restrict__ elist,
                                              const float* __restrict__ eps, int l,
                                              float* __restrict__ z) {
    const int dst = blockIdx.x;
    const int c = threadIdx.x;
    float wb[FE];
    #pragma unroll
    for (int k = 0; k < FE; ++k) wb[k] = bond_w[k * H + c];   // L1-hot
    const float bb = bond_b[c];
    float acc = (1.0f + eps[l]) * h[(size_t)dst * H + c];
    const int lo = rowptr[dst], hi = rowptr[dst + 1];
    for (int t = lo; t < hi; ++t) {
        const int e = elist[t];              // uniform across block
        const int src = ei[e];
        float ev = bb;
        #pragma unroll
        for (int k = 0; k < FE; ++k) ev += eattr[(size_t)e * FE + k] * wb[k];
        const float hv = h[(size_t)src * H + c];
        acc += fmaxf(hv + ev, 0.0f);
    }
    z[(size_t)dst * H + c] = acc;
}

// ---------------- tiled fp32 GEMM with fused BN(+bias)+relu (+residual) ----------------
template <int EPI>  // 0: relu(bn(acc+bias))   1: ... + res (res may alias C)
__global__ __launch_bounds__(256) void gemm_bn(const float* __restrict__ A,
                                               const float* __restrict__ B,
                                               int K, int Ncols,
                                               const float* __restrict__ bias,
                                               const float* __restrict__ bng,
                                               const float* __restrict__ bnb,
                                               const float* __restrict__ bnm,
                                               const float* __restrict__ bnv,
                                               float* __restrict__ C,
                                               const float* __restrict__ res) {
    __shared__ float As[16][128];
    __shared__ float Bs[16][64];
    const int tid = threadIdx.x;
    const int tm = tid >> 4;
    const int tn = tid & 15;
    const int m0 = blockIdx.y * 128;
    const int n0 = blockIdx.x * 64;

    const int lr = tid >> 2;
    const int lk = (tid & 3) * 4;
    const int kb = tid >> 4;
    const int nq = (tid & 15) * 4;

    const float* Arow0 = A + (size_t)(m0 + lr) * K + lk;
    const float* Arow1 = A + (size_t)(m0 + lr + 64) * K + lk;
    const float* Bptr  = B + (size_t)kb * Ncols + n0 + nq;

    float acc[8][4];
    #pragma unroll
    for (int i = 0; i < 8; ++i)
        #pragma unroll
        for (int j = 0; j < 4; ++j) acc[i][j] = 0.0f;

    for (int k0 = 0; k0 < K; k0 += 16) {
        const float4 a0 = *(const float4*)(Arow0 + k0);
        const float4 a1 = *(const float4*)(Arow1 + k0);
        const float4 b0 = *(const float4*)(Bptr + (size_t)k0 * Ncols);
        __syncthreads();
        As[lk + 0][lr] = a0.x;  As[lk + 1][lr] = a0.y;
        As[lk + 2][lr] = a0.z;  As[lk + 3][lr] = a0.w;
        As[lk + 0][lr + 64] = a1.x;  As[lk + 1][lr + 64] = a1.y;
        As[lk + 2][lr + 64] = a1.z;  As[lk + 3][lr + 64] = a1.w;
        *(float4*)&Bs[kb][nq] = b0;
        __syncthreads();
        #pragma unroll
        for (int kk = 0; kk < 16; ++kk) {
            const float4 av0 = *(const float4*)&As[kk][tm * 8];
            const float4 av1 = *(const float4*)&As[kk][tm * 8 + 4];
            const float4 bv  = *(const float4*)&Bs[kk][tn * 4];
            const float a_[8] = {av0.x, av0.y, av0.z, av0.w, av1.x, av1.y, av1.z, av1.w};
            const float b_[4] = {bv.x, bv.y, bv.z, bv.w};
            #pragma unroll
            for (int i = 0; i < 8; ++i)
                #pragma unroll
                for (int j = 0; j < 4; ++j) acc[i][j] += a_[i] * b_[j];
        }
    }

    float scale[4], shift[4];
    #pragma unroll
    for (int j = 0; j < 4; ++j) {
        const int c = n0 + tn * 4 + j;
        const float s = bng[c] * rsqrtf(bnv[c] + BN_EPS);
        scale[j] = s;
        shift[j] = s * (bias[c] - bnm[c]) + bnb[c];
    }
    #pragma unroll
    for (int i = 0; i < 8; ++i) {
        const size_t off = (size_t)(m0 + tm * 8 + i) * Ncols + n0 + tn * 4;
        float4 rv = make_float4(0.f, 0.f, 0.f, 0.f);
        if (EPI == 1) rv = *(const float4*)(res + off);
        float4 o;
        o.x = fmaxf(scale[0] * acc[i][0] + shift[0], 0.f) + rv.x;
        o.y = fmaxf(scale[1] * acc[i][1] + shift[1], 0.f) + rv.y;
        o.z = fmaxf(scale[2] * acc[i][2] + shift[2], 0.f) + rv.z;
        o.w = fmaxf(scale[3] * acc[i][3] + shift[3], 0.f) + rv.w;
        *(float4*)(C + off) = o;
    }
}

// ---------------- pooling: mean + max per graph ----------------
__global__ __launch_bounds__(H) void pool_kernel(const float* __restrict__ h,
                                                 const int* __restrict__ batch,
                                                 float* __restrict__ p) {
    const int g = blockIdx.x;
    const int c = threadIdx.x;
    int lo, hi;
    {
        int a = 0, b = NA;
        while (a < b) { int mid = (a + b) >> 1; if (batch[mid] < g) a = mid + 1; else b = mid; }
        lo = a;
        b = NA;
        while (a < b) { int mid = (a + b) >> 1; if (batch[mid] < g + 1) a = mid + 1; else b = mid; }
        hi = a;
    }
    float sum = 0.0f, mx = -INFINITY;
    for (int n = lo; n < hi; ++n) {
        const float v = h[(size_t)n * H + c];
        sum += v;
        mx = fmaxf(mx, v);
    }
    const int cnt = hi - lo;
    const float mean = (cnt > 0) ? sum / (float)cnt : 0.0f;
    if (cnt == 0) mx = 0.0f;
    p[(size_t)g * H2 + c] = mean;
    p[(size_t)g * H2 + H + c] = mx;
}

// ---------------- classifier row-MLP ----------------
template <int Kdim, int Ncols>
__global__ __launch_bounds__(Ncols) void rowmlp(const float* __restrict__ A,
                                                const float* __restrict__ W,
                                                const float* __restrict__ bias,
                                                const float* __restrict__ bg,
                                                const float* __restrict__ bb,
                                                const float* __restrict__ bm,
                                                const float* __restrict__ bv,
                                                float* __restrict__ out) {
    __shared__ float as[Kdim];
    const int row = blockIdx.x;
    const int c = threadIdx.x;
    for (int k = c; k < Kdim; k += Ncols) as[k] = A[(size_t)row * Kdim + k];
    __syncthreads();
    float acc = 0.0f;
    #pragma unroll 8
    for (int k = 0; k < Kdim; ++k) acc += as[k] * W[k * Ncols + c];
    const float s = bg[c] * rsqrtf(bv[c] + BN_EPS);
    const float val = s * (acc + bias[c] - bm[c]) + bb[c];
    out[(size_t)row * Ncols + c] = fmaxf(val, 0.0f);
}

__global__ __launch_bounds__(64) void final_out(const float* __restrict__ q2,
                                                const float* __restrict__ w,
                                                const float* __restrict__ b,
                                                float* __restrict__ out) {
    const int g = blockIdx.x;
    const int lane = threadIdx.x;
    float acc = q2[(size_t)g * 128 + lane] * w[lane]
              + q2[(size_t)g * 128 + 64 + lane] * w[64 + lane];
    #pragma unroll
    for (int off = 32; off > 0; off >>= 1) acc += __shfl_down(acc, off);
    if (lane == 0) out[g] = acc + b[0];
}

// ---------------- launch ----------------
extern "C" void kernel_launch(void* const* d_in, const int* in_sizes, int n_in,
                              void* d_out, int out_size, void* d_ws, size_t ws_size,
                              hipStream_t stream) {
    const float* x      = (const float*)d_in[0];
    const int*   ei     = (const int*)d_in[1];
    const int*   batch  = (const int*)d_in[2];
    const float* eattr  = (const float*)d_in[3];
    const float* enc_w  = (const float*)d_in[4];
    const float* enc_b  = (const float*)d_in[5];
    const float* bond_w = (const float*)d_in[6];
    const float* bond_b = (const float*)d_in[7];
    const float* eps    = (const float*)d_in[8];
    const float* w1     = (const float*)d_in[9];
    const float* b1     = (const float*)d_in[10];
    const float* ibn_g  = (const float*)d_in[11];
    const float* ibn_b  = (const float*)d_in[12];
    const float* ibn_m  = (const float*)d_in[13];
    const float* ibn_v  = (const float*)d_in[14];
    const float* w2     = (const float*)d_in[15];
    const float* b2     = (const float*)d_in[16];
    const float* obn_g  = (const float*)d_in[17];
    const float* obn_b  = (const float*)d_in[18];
    const float* obn_m  = (const float*)d_in[19];
    const float* obn_v  = (const float*)d_in[20];
    const float* cw1    = (const float*)d_in[21];
    const float* cb1    = (const float*)d_in[22];
    const float* c1g    = (const float*)d_in[23];
    const float* c1b    = (const float*)d_in[24];
    const float* c1m    = (const float*)d_in[25];
    const float* c1v    = (const float*)d_in[26];
    const float* cw2    = (const float*)d_in[27];
    const float* cb2    = (const float*)d_in[28];
    const float* c2g    = (const float*)d_in[29];
    const float* c2b    = (const float*)d_in[30];
    const float* c2m    = (const float*)d_in[31];
    const float* c2v    = (const float*)d_in[32];
    const float* cw3    = (const float*)d_in[33];
    const float* cb3    = (const float*)d_in[34];
    float* out = (float*)d_out;

    // ---- workspace selection (deterministic per run) ----
    // Layout: [csr ints: CSR_WORDS][h: NA*H][z: NA*H][z1: up to NA*H2]
    const size_t need_full = ((size_t)CSR_WORDS + (size_t)NA * H * 2 + (size_t)NA * H2) * 4;
    float* buf;
    size_t buf_bytes;
    if (ws_size >= need_full) { buf = (float*)d_ws; buf_bytes = ws_size; }
    else if (g_buf)           { buf = g_buf;        buf_bytes = need_full; }
    else                      { buf = (float*)d_ws; buf_bytes = ws_size; }

    int* deg    = (int*)buf;                 // NA
    int* rowptr = deg + NA;                  // NA+1
    int* cursor = rowptr + NA + 1;           // NA
    int* elist  = cursor + NA;               // NE

    float* h   = buf + CSR_WORDS;
    float* z   = h + (size_t)NA * H;
    float* z1c = z + (size_t)NA * H;

    const size_t base_f  = (size_t)CSR_WORDS + (size_t)NA * H * 2;
    const size_t avail_f = (buf_bytes / 4 > base_f) ? buf_bytes / 4 - base_f : 0;
    int CH = (int)(avail_f / H2);
    CH &= ~127;
    if (CH > NA) CH = NA;
    if (CH < 128) CH = 128;

    float* p  = z;                    // NG*H2   (z dead after last layer)
    float* q1 = p + (size_t)NG * H2;  // NG*H
    float* q2 = q1 + (size_t)NG * H;  // NG*(H/2)

    // ---- CSR build (once; edges are layer-invariant) ----
    hipMemsetAsync(deg, 0, (size_t)NA * 4, stream);
    count_deg<<<NE / 256, 256, 0, stream>>>(ei, deg);
    scan_deg<<<1, 1024, 0, stream>>>(deg, rowptr, cursor);
    fill_elist<<<NE / 256, 256, 0, stream>>>(ei, cursor, elist);

    encode_nodes<<<NA, H, 0, stream>>>(x, enc_w, enc_b, h);

    for (int l = 0; l < NL; ++l) {
        gine_msg<<<NA, H, 0, stream>>>(h, eattr, bond_w, bond_b, ei, rowptr, elist,
                                       eps, l, z);
        for (int r0 = 0; r0 < NA; r0 += CH) {
            const int CHc = (NA - r0 < CH) ? (NA - r0) : CH;
            dim3 g1(H2 / 64, CHc / 128);
            gemm_bn<0><<<g1, 256, 0, stream>>>(z + (size_t)r0 * H,
                                               w1 + (size_t)l * H * H2, H, H2,
                                               b1 + (size_t)l * H2, ibn_g + (size_t)l * H2,
                                               ibn_b + (size_t)l * H2, ibn_m + (size_t)l * H2,
                                               ibn_v + (size_t)l * H2, z1c, nullptr);
            dim3 g2(H / 64, CHc / 128);
            gemm_bn<1><<<g2, 256, 0, stream>>>(z1c, w2 + (size_t)l * H2 * H, H2, H,
                                               b2 + (size_t)l * H, obn_g + (size_t)l * H,
                                               obn_b + (size_t)l * H, obn_m + (size_t)l * H,
                                               obn_v + (size_t)l * H,
                                               h + (size_t)r0 * H, h + (size_t)r0 * H);
        }
    }

    pool_kernel<<<NG, H, 0, stream>>>(h, batch, p);
    rowmlp<H2, H><<<NG, H, 0, stream>>>(p, cw1, cb1, c1g, c1b, c1m, c1v, q1);
    rowmlp<H, H / 2><<<NG, H / 2, 0, stream>>>(q1, cw2, cb2, c2g, c2b, c2m, c2v, q2);
    final_out<<<NG, 64, 0, stream>>>(q2, cw3, cb3, out);
}

// Round 5
// 3117.887 us; speedup vs baseline: 2.8636x; 1.7647x over previous
//
#include <hip/hip_runtime.h>
#include <math.h>

#define NA 131072   // atoms
#define NE 262144   // edges
#define NG 4096     // graphs
#define FN 30
#define FE 11
#define H  256
#define H2 512
#define NL 5
#define BN_EPS 1e-5f

typedef short s16x8 __attribute__((ext_vector_type(8)));
typedef float f32x4 __attribute__((ext_vector_type(4)));

__device__ __forceinline__ unsigned short f2bf(float f) {
    unsigned u = __float_as_uint(f);
    u = u + 0x7FFFu + ((u >> 16) & 1u);          // RNE
    return (unsigned short)(u >> 16);
}
__device__ __forceinline__ float bf2f(unsigned short s) {
    return __uint_as_float((unsigned)s << 16);
}

// ---- private fallback workspace, allocated ONCE at library load ----
static float* g_buf = nullptr;
__attribute__((constructor)) static void _alloc_private_ws() {
    void* p = nullptr;
    if (hipMalloc(&p, (size_t)552 * 1024 * 1024) == hipSuccess) g_buf = (float*)p;
}

// ---------------- weight prep: transpose + bf16 hi/lo split ----------------
// w: [K][N] row-major fp32  ->  hiT/loT: [N][K] bf16 bits
__global__ __launch_bounds__(256) void prep_w(const float* __restrict__ w, int K, int N,
                                              unsigned short* __restrict__ hiT,
                                              unsigned short* __restrict__ loT) {
    __shared__ float t[32][33];
    const int k0 = blockIdx.x * 32, n0 = blockIdx.y * 32;
    const int tx = threadIdx.x & 31, ty = threadIdx.x >> 5;   // ty 0..7
    #pragma unroll
    for (int i = 0; i < 4; ++i)
        t[ty + i * 8][tx] = w[(size_t)(k0 + ty + i * 8) * N + n0 + tx];
    __syncthreads();
    #pragma unroll
    for (int i = 0; i < 4; ++i) {
        const float f = t[tx][ty + i * 8];                    // (k0+tx, n0+ty+8i)
        const unsigned short hi = f2bf(f);
        const unsigned short lo = f2bf(f - bf2f(hi));
        const size_t o = (size_t)(n0 + ty + i * 8) * K + k0 + tx;
        hiT[o] = hi;
        loT[o] = lo;
    }
}

// ---------------- node encoder ----------------
__global__ __launch_bounds__(H) void encode_nodes(const float* __restrict__ x,
                                                  const float* __restrict__ w,
                                                  const float* __restrict__ b,
                                                  float* __restrict__ h) {
    __shared__ float xs[FN];
    const int row = blockIdx.x;
    const int c = threadIdx.x;
    if (c < FN) xs[c] = x[(size_t)row * FN + c];
    __syncthreads();
    float acc = b[c];
    #pragma unroll
    for (int k = 0; k < FN; ++k) acc += xs[k] * w[k * H + c];
    h[(size_t)row * H + c] = acc;
}

// ---------------- CSR build (once per call) ----------------
__global__ __launch_bounds__(256) void count_deg(const int* __restrict__ ei,
                                                 int* __restrict__ deg) {
    const int e = blockIdx.x * 256 + threadIdx.x;
    if (e < NE) atomicAdd(&deg[ei[NE + e]], 1);
}

__global__ __launch_bounds__(1024) void scan_deg(const int* __restrict__ deg,
                                                 int* __restrict__ rowptr,
                                                 int* __restrict__ cursor) {
    __shared__ int part[1024];
    const int t = threadIdx.x;
    const int base = t * 128;               // 1024*128 == NA
    int s = 0;
    #pragma unroll 8
    for (int i = 0; i < 128; ++i) s += deg[base + i];
    part[t] = s;
    __syncthreads();
    for (int off = 1; off < 1024; off <<= 1) {
        const int v = (t >= off) ? part[t - off] : 0;
        __syncthreads();
        part[t] += v;
        __syncthreads();
    }
    int run = (t == 0) ? 0 : part[t - 1];
    #pragma unroll 8
    for (int i = 0; i < 128; ++i) {
        rowptr[base + i] = run;
        cursor[base + i] = run;
        run += deg[base + i];
    }
    if (t == 1023) rowptr[NA] = run;        // == NE
}

__global__ __launch_bounds__(256) void fill_elist(const int* __restrict__ ei,
                                                  int* __restrict__ cursor,
                                                  int* __restrict__ elist) {
    const int e = blockIdx.x * 256 + threadIdx.x;
    if (e < NE) {
        const int pos = atomicAdd(&cursor[ei[NE + e]], 1);
        elist[pos] = e;
    }
}

// ---- GINE aggregation (gather form): z[dst] = (1+eps)h[dst] + sum relu(h[src]+bond) ----
__global__ __launch_bounds__(H) void gine_msg(const float* __restrict__ h,
                                              const float* __restrict__ eattr,
                                              const float* __restrict__ bond_w,
                                              const float* __restrict__ bond_b,
                                              const int* __restrict__ ei,
                                              const int* __restrict__ rowptr,
                                              const int* __restrict__ elist,
                                              const float* __restrict__ eps, int l,
                                              float* __restrict__ z) {
    const int dst = blockIdx.x;
    const int c = threadIdx.x;
    float wb[FE];
    #pragma unroll
    for (int k = 0; k < FE; ++k) wb[k] = bond_w[k * H + c];   // L1-hot
    const float bb = bond_b[c];
    float acc = (1.0f + eps[l]) * h[(size_t)dst * H + c];
    const int lo = rowptr[dst], hi = rowptr[dst + 1];
    for (int t = lo; t < hi; ++t) {
        const int e = elist[t];              // uniform across block
        const int src = ei[e];
        float ev = bb;
        #pragma unroll
        for (int k = 0; k < FE; ++k) ev += eattr[(size_t)e * FE + k] * wb[k];
        const float hv = h[(size_t)src * H + c];
        acc += fmaxf(hv + ev, 0.0f);
    }
    z[(size_t)dst * H + c] = acc;
}

// ---------------- split-bf16 3-pass MFMA GEMM, fused BN(+bias)+relu(+residual) ----------
// C[M,Ncols] = epi(A[M,KDIM] @ B) ; B given pre-transposed+split: BTh/BTl = [Ncols][KDIM]
// tile 128x128, BK=32, 256 thr = 4 waves (2x2), wave tile 64x64 (4x4 frags of 16x16x32)
template <int KDIM, int EPI>
__global__ __launch_bounds__(256, 2) void gemm_mfma(
    const float* __restrict__ A,
    const unsigned short* __restrict__ BTh,
    const unsigned short* __restrict__ BTl,
    int Ncols,
    const float* __restrict__ bias, const float* __restrict__ bng,
    const float* __restrict__ bnb, const float* __restrict__ bnm,
    const float* __restrict__ bnv,
    float* __restrict__ C, const float* __restrict__ res)
{
    __shared__ __align__(16) unsigned short As_hi[128][40];   // pad 32->40: 2-way max
    __shared__ __align__(16) unsigned short As_lo[128][40];
    __shared__ __align__(16) unsigned short Bs_hi[128][40];
    __shared__ __align__(16) unsigned short Bs_lo[128][40];

    const int tid = threadIdx.x;
    const int nt = Ncols >> 7;                 // n-tiles
    // XCD-bijective swizzle (m204): contiguous M-range per XCD
    const int nwg = gridDim.x, orig = blockIdx.x;
    const int q = nwg >> 3, r = nwg & 7;
    const int xcd = orig & 7, rk = orig >> 3;
    const int wg = (xcd < r ? xcd * (q + 1) : r * (q + 1) + (xcd - r) * q) + rk;
    const int m0 = (wg / nt) * 128;
    const int n0 = (wg % nt) * 128;

    const int wid = tid >> 6, lane = tid & 63;
    const int wm = wid >> 1, wn = wid & 1;
    const int lrow = lane & 15, lgrp = lane >> 4;
    const int sr = tid >> 3;                   // staging row 0..31
    const int sk = (tid & 7) * 4;              // staging k 0,4,..,28

    f32x4 acc[4][4];
    const f32x4 zero4 = {0.0f, 0.0f, 0.0f, 0.0f};
    #pragma unroll
    for (int i = 0; i < 4; ++i)
        #pragma unroll
        for (int j = 0; j < 4; ++j) acc[i][j] = zero4;

    for (int k0 = 0; k0 < KDIM; k0 += 32) {
        float4 av[4]; ushort4 gh[4], gl[4];
        #pragma unroll
        for (int i = 0; i < 4; ++i) {
            const int rr = sr + i * 32;
            av[i] = *(const float4*)(A + (size_t)(m0 + rr) * KDIM + k0 + sk);
            gh[i] = *(const ushort4*)(BTh + (size_t)(n0 + rr) * KDIM + k0 + sk);
            gl[i] = *(const ushort4*)(BTl + (size_t)(n0 + rr) * KDIM + k0 + sk);
        }
        __syncthreads();                       // prev iter's LDS reads done
        #pragma unroll
        for (int i = 0; i < 4; ++i) {
            const int rr = sr + i * 32;
            ushort4 hv, lv;
            hv.x = f2bf(av[i].x); lv.x = f2bf(av[i].x - bf2f(hv.x));
            hv.y = f2bf(av[i].y); lv.y = f2bf(av[i].y - bf2f(hv.y));
            hv.z = f2bf(av[i].z); lv.z = f2bf(av[i].z - bf2f(hv.z));
            hv.w = f2bf(av[i].w); lv.w = f2bf(av[i].w - bf2f(hv.w));
            *(ushort4*)&As_hi[rr][sk] = hv;
            *(ushort4*)&As_lo[rr][sk] = lv;
            *(ushort4*)&Bs_hi[rr][sk] = gh[i];
            *(ushort4*)&Bs_lo[rr][sk] = gl[i];
        }
        __syncthreads();
        s16x8 ah[4], al[4], bh[4], bl[4];
        #pragma unroll
        for (int mi = 0; mi < 4; ++mi) {
            const int ar = wm * 64 + mi * 16 + lrow;
            ah[mi] = *(const s16x8*)&As_hi[ar][lgrp * 8];
            al[mi] = *(const s16x8*)&As_lo[ar][lgrp * 8];
        }
        #pragma unroll
        for (int ni = 0; ni < 4; ++ni) {
            const int bc = wn * 64 + ni * 16 + lrow;
            bh[ni] = *(const s16x8*)&Bs_hi[bc][lgrp * 8];
            bl[ni] = *(const s16x8*)&Bs_lo[bc][lgrp * 8];
        }
        #pragma unroll
        for (int mi = 0; mi < 4; ++mi)
            #pragma unroll
            for (int ni = 0; ni < 4; ++ni) {
                acc[mi][ni] = __builtin_amdgcn_mfma_f32_16x16x32_bf16(ah[mi], bh[ni], acc[mi][ni], 0, 0, 0);
                acc[mi][ni] = __builtin_amdgcn_mfma_f32_16x16x32_bf16(al[mi], bh[ni], acc[mi][ni], 0, 0, 0);
                acc[mi][ni] = __builtin_amdgcn_mfma_f32_16x16x32_bf16(ah[mi], bl[ni], acc[mi][ni], 0, 0, 0);
            }
    }

    // epilogue: per-column scale/shift, relu, optional residual (res may alias C)
    float scl[4], shf[4];
    #pragma unroll
    for (int ni = 0; ni < 4; ++ni) {
        const int c = n0 + wn * 64 + ni * 16 + lrow;
        const float s = bng[c] * rsqrtf(bnv[c] + BN_EPS);
        scl[ni] = s;
        shf[ni] = s * (bias[c] - bnm[c]) + bnb[c];
    }
    #pragma unroll
    for (int mi = 0; mi < 4; ++mi)
        #pragma unroll
        for (int j = 0; j < 4; ++j) {
            const int row = m0 + wm * 64 + mi * 16 + lgrp * 4 + j;
            #pragma unroll
            for (int ni = 0; ni < 4; ++ni) {
                const int col = n0 + wn * 64 + ni * 16 + lrow;
                float v = fmaxf(scl[ni] * acc[mi][ni][j] + shf[ni], 0.0f);
                if (EPI == 1) v += res[(size_t)row * Ncols + col];
                C[(size_t)row * Ncols + col] = v;
            }
        }
}

// ---------------- pooling: mean + max per graph ----------------
__global__ __launch_bounds__(H) void pool_kernel(const float* __restrict__ h,
                                                 const int* __restrict__ batch,
                                                 float* __restrict__ p) {
    const int g = blockIdx.x;
    const int c = threadIdx.x;
    int lo, hi;
    {
        int a = 0, b = NA;
        while (a < b) { int mid = (a + b) >> 1; if (batch[mid] < g) a = mid + 1; else b = mid; }
        lo = a;
        b = NA;
        while (a < b) { int mid = (a + b) >> 1; if (batch[mid] < g + 1) a = mid + 1; else b = mid; }
        hi = a;
    }
    float sum = 0.0f, mx = -INFINITY;
    for (int n = lo; n < hi; ++n) {
        const float v = h[(size_t)n * H + c];
        sum += v;
        mx = fmaxf(mx, v);
    }
    const int cnt = hi - lo;
    const float mean = (cnt > 0) ? sum / (float)cnt : 0.0f;
    if (cnt == 0) mx = 0.0f;
    p[(size_t)g * H2 + c] = mean;
    p[(size_t)g * H2 + H + c] = mx;
}

// ---------------- classifier row-MLP ----------------
template <int Kdim, int Ncols>
__global__ __launch_bounds__(Ncols) void rowmlp(const float* __restrict__ A,
                                                const float* __restrict__ W,
                                                const float* __restrict__ bias,
                                                const float* __restrict__ bg,
                                                const float* __restrict__ bb,
                                                const float* __restrict__ bm,
                                                const float* __restrict__ bv,
                                                float* __restrict__ out) {
    __shared__ float as[Kdim];
    const int row = blockIdx.x;
    const int c = threadIdx.x;
    for (int k = c; k < Kdim; k += Ncols) as[k] = A[(size_t)row * Kdim + k];
    __syncthreads();
    float acc = 0.0f;
    #pragma unroll 8
    for (int k = 0; k < Kdim; ++k) acc += as[k] * W[k * Ncols + c];
    const float s = bg[c] * rsqrtf(bv[c] + BN_EPS);
    const float val = s * (acc + bias[c] - bm[c]) + bb[c];
    out[(size_t)row * Ncols + c] = fmaxf(val, 0.0f);
}

__global__ __launch_bounds__(64) void final_out(const float* __restrict__ q2,
                                                const float* __restrict__ w,
                                                const float* __restrict__ b,
                                                float* __restrict__ out) {
    const int g = blockIdx.x;
    const int lane = threadIdx.x;
    float acc = q2[(size_t)g * 128 + lane] * w[lane]
              + q2[(size_t)g * 128 + 64 + lane] * w[64 + lane];
    #pragma unroll
    for (int off = 32; off > 0; off >>= 1) acc += __shfl_down(acc, off);
    if (lane == 0) out[g] = acc + b[0];
}

// ---------------- launch ----------------
extern "C" void kernel_launch(void* const* d_in, const int* in_sizes, int n_in,
                              void* d_out, int out_size, void* d_ws, size_t ws_size,
                              hipStream_t stream) {
    const float* x      = (const float*)d_in[0];
    const int*   ei     = (const int*)d_in[1];
    const int*   batch  = (const int*)d_in[2];
    const float* eattr  = (const float*)d_in[3];
    const float* enc_w  = (const float*)d_in[4];
    const float* enc_b  = (const float*)d_in[5];
    const float* bond_w = (const float*)d_in[6];
    const float* bond_b = (const float*)d_in[7];
    const float* eps    = (const float*)d_in[8];
    const float* w1     = (const float*)d_in[9];
    const float* b1     = (const float*)d_in[10];
    const float* ibn_g  = (const float*)d_in[11];
    const float* ibn_b  = (const float*)d_in[12];
    const float* ibn_m  = (const float*)d_in[13];
    const float* ibn_v  = (const float*)d_in[14];
    const float* w2     = (const float*)d_in[15];
    const float* b2     = (const float*)d_in[16];
    const float* obn_g  = (const float*)d_in[17];
    const float* obn_b  = (const float*)d_in[18];
    const float* obn_m  = (const float*)d_in[19];
    const float* obn_v  = (const float*)d_in[20];
    const float* cw1    = (const float*)d_in[21];
    const float* cb1    = (const float*)d_in[22];
    const float* c1g    = (const float*)d_in[23];
    const float* c1b    = (const float*)d_in[24];
    const float* c1m    = (const float*)d_in[25];
    const float* c1v    = (const float*)d_in[26];
    const float* cw2    = (const float*)d_in[27];
    const float* cb2    = (const float*)d_in[28];
    const float* c2g    = (const float*)d_in[29];
    const float* c2b    = (const float*)d_in[30];
    const float* c2m    = (const float*)d_in[31];
    const float* c2v    = (const float*)d_in[32];
    const float* cw3    = (const float*)d_in[33];
    const float* cb3    = (const float*)d_in[34];
    float* out = (float*)d_out;

    // ---- workspace layout ----
    // [w1Th|w1Tl|w2Th|w2Tl: 4 x 5*H*H2 ushort][csr ints][h: NA*H f32][z: NA*H f32][z1: NA*H2 f32]
    const size_t WT = (size_t)NL * H * H2;                      // elems per plane
    const size_t wt_bytes  = 4 * WT * sizeof(unsigned short);   // 5.24 MB
    const size_t csr_bytes = ((size_t)3 * NA + 1 + NE) * 4;     // 2.62 MB
    const size_t hz_bytes  = (size_t)NA * H * 2 * 4;            // 268 MB
    const size_t z1_bytes  = (size_t)NA * H2 * 4;               // 268 MB
    const size_t need_full = wt_bytes + csr_bytes + hz_bytes + z1_bytes;

    float* buf;
    size_t buf_bytes;
    if (ws_size >= need_full) { buf = (float*)d_ws; buf_bytes = ws_size; }
    else if (g_buf)           { buf = g_buf;        buf_bytes = need_full; }
    else                      { buf = (float*)d_ws; buf_bytes = ws_size; }

    unsigned short* w1Th = (unsigned short*)buf;
    unsigned short* w1Tl = w1Th + WT;
    unsigned short* w2Th = w1Tl + WT;
    unsigned short* w2Tl = w2Th + WT;
    int* deg    = (int*)(w2Tl + WT);
    int* rowptr = deg + NA;
    int* cursor = rowptr + NA + 1;
    int* elist  = cursor + NA;
    float* h   = (float*)(elist + NE);
    float* z   = h + (size_t)NA * H;
    float* z1c = z + (size_t)NA * H;

    const size_t fixed_bytes = wt_bytes + csr_bytes + hz_bytes;
    const size_t avail_f = (buf_bytes > fixed_bytes) ? (buf_bytes - fixed_bytes) / 4 : 0;
    int CH = (int)(avail_f / H2);
    CH &= ~127;
    if (CH > NA) CH = NA;
    if (CH < 128) CH = 128;

    float* p  = z;                    // NG*H2 (z dead after last layer)
    float* q1 = p + (size_t)NG * H2;  // NG*H
    float* q2 = q1 + (size_t)NG * H;  // NG*(H/2)

    // ---- weight prep (transpose + hi/lo split), once per call ----
    for (int l = 0; l < NL; ++l) {
        prep_w<<<dim3(H / 32, H2 / 32), 256, 0, stream>>>(
            w1 + (size_t)l * H * H2, H, H2, w1Th + (size_t)l * H * H2, w1Tl + (size_t)l * H * H2);
        prep_w<<<dim3(H2 / 32, H / 32), 256, 0, stream>>>(
            w2 + (size_t)l * H2 * H, H2, H, w2Th + (size_t)l * H2 * H, w2Tl + (size_t)l * H2 * H);
    }

    // ---- CSR build (edges are layer-invariant) ----
    hipMemsetAsync(deg, 0, (size_t)NA * 4, stream);
    count_deg<<<NE / 256, 256, 0, stream>>>(ei, deg);
    scan_deg<<<1, 1024, 0, stream>>>(deg, rowptr, cursor);
    fill_elist<<<NE / 256, 256, 0, stream>>>(ei, cursor, elist);

    encode_nodes<<<NA, H, 0, stream>>>(x, enc_w, enc_b, h);

    for (int l = 0; l < NL; ++l) {
        gine_msg<<<NA, H, 0, stream>>>(h, eattr, bond_w, bond_b, ei, rowptr, elist,
                                       eps, l, z);
        for (int r0 = 0; r0 < NA; r0 += CH) {
            const int CHc = (NA - r0 < CH) ? (NA - r0) : CH;
            gemm_mfma<H, 0><<<(CHc / 128) * (H2 / 128), 256, 0, stream>>>(
                z + (size_t)r0 * H, w1Th + (size_t)l * H * H2, w1Tl + (size_t)l * H * H2, H2,
                b1 + (size_t)l * H2, ibn_g + (size_t)l * H2, ibn_b + (size_t)l * H2,
                ibn_m + (size_t)l * H2, ibn_v + (size_t)l * H2, z1c, nullptr);
            gemm_mfma<H2, 1><<<(CHc / 128) * (H / 128), 256, 0, stream>>>(
                z1c, w2Th + (size_t)l * H2 * H, w2Tl + (size_t)l * H2 * H, H,
                b2 + (size_t)l * H, obn_g + (size_t)l * H, obn_b + (size_t)l * H,
                obn_m + (size_t)l * H, obn_v + (size_t)l * H,
                h + (size_t)r0 * H, h + (size_t)r0 * H);
        }
    }

    pool_kernel<<<NG, H, 0, stream>>>(h, batch, p);
    rowmlp<H2, H><<<NG, H, 0, stream>>>(p, cw1, cb1, c1g, c1b, c1m, c1v, q1);
    rowmlp<H, H / 2><<<NG, H / 2, 0, stream>>>(q1, cw2, cb2, c2g, c2b, c2m, c2v, q2);
    final_out<<<NG, 64, 0, stream>>>(q2, cw3, cb3, out);
}

// Round 6
// 2783.992 us; speedup vs baseline: 3.2070x; 1.1199x over previous
//
#include <hip/hip_runtime.h>
#include <math.h>

#define NA 131072   // atoms
#define NE 262144   // edges
#define NG 4096     // graphs
#define FN 30
#define FE 11
#define H  256
#define H2 512
#define NL 5
#define BN_EPS 1e-5f

typedef short s16x8 __attribute__((ext_vector_type(8)));
typedef float f32x4 __attribute__((ext_vector_type(4)));

__device__ __forceinline__ unsigned short f2bf(float f) {
    unsigned u = __float_as_uint(f);
    u = u + 0x7FFFu + ((u >> 16) & 1u);          // RNE
    return (unsigned short)(u >> 16);
}
__device__ __forceinline__ float bf2f(unsigned short s) {
    return __uint_as_float((unsigned)s << 16);
}

// ---- private fallback workspace, allocated ONCE at library load ----
static float* g_buf = nullptr;
__attribute__((constructor)) static void _alloc_private_ws() {
    void* p = nullptr;
    if (hipMalloc(&p, (size_t)552 * 1024 * 1024) == hipSuccess) g_buf = (float*)p;
}

// ---------------- weight prep: transpose + bf16 hi/lo split ----------------
__global__ __launch_bounds__(256) void prep_w(const float* __restrict__ w, int K, int N,
                                              unsigned short* __restrict__ hiT,
                                              unsigned short* __restrict__ loT) {
    __shared__ float t[32][33];
    const int k0 = blockIdx.x * 32, n0 = blockIdx.y * 32;
    const int tx = threadIdx.x & 31, ty = threadIdx.x >> 5;   // ty 0..7
    #pragma unroll
    for (int i = 0; i < 4; ++i)
        t[ty + i * 8][tx] = w[(size_t)(k0 + ty + i * 8) * N + n0 + tx];
    __syncthreads();
    #pragma unroll
    for (int i = 0; i < 4; ++i) {
        const float f = t[tx][ty + i * 8];                    // (k0+tx, n0+ty+8i)
        const unsigned short hi = f2bf(f);
        const unsigned short lo = f2bf(f - bf2f(hi));
        const size_t o = (size_t)(n0 + ty + i * 8) * K + k0 + tx;
        hiT[o] = hi;
        loT[o] = lo;
    }
}

// ---------------- node encoder ----------------
__global__ __launch_bounds__(H) void encode_nodes(const float* __restrict__ x,
                                                  const float* __restrict__ w,
                                                  const float* __restrict__ b,
                                                  float* __restrict__ h) {
    __shared__ float xs[FN];
    const int row = blockIdx.x;
    const int c = threadIdx.x;
    if (c < FN) xs[c] = x[(size_t)row * FN + c];
    __syncthreads();
    float acc = b[c];
    #pragma unroll
    for (int k = 0; k < FN; ++k) acc += xs[k] * w[k * H + c];
    h[(size_t)row * H + c] = acc;
}

// ---------------- CSR build (once per call) ----------------
__global__ __launch_bounds__(256) void count_deg(const int* __restrict__ ei,
                                                 int* __restrict__ deg) {
    const int e = blockIdx.x * 256 + threadIdx.x;
    if (e < NE) atomicAdd(&deg[ei[NE + e]], 1);
}

__global__ __launch_bounds__(1024) void scan_deg(const int* __restrict__ deg,
                                                 int* __restrict__ rowptr,
                                                 int* __restrict__ cursor) {
    __shared__ int part[1024];
    const int t = threadIdx.x;
    const int base = t * 128;               // 1024*128 == NA
    int s = 0;
    #pragma unroll 8
    for (int i = 0; i < 128; ++i) s += deg[base + i];
    part[t] = s;
    __syncthreads();
    for (int off = 1; off < 1024; off <<= 1) {
        const int v = (t >= off) ? part[t - off] : 0;
        __syncthreads();
        part[t] += v;
        __syncthreads();
    }
    int run = (t == 0) ? 0 : part[t - 1];
    #pragma unroll 8
    for (int i = 0; i < 128; ++i) {
        rowptr[base + i] = run;
        cursor[base + i] = run;
        run += deg[base + i];
    }
    if (t == 1023) rowptr[NA] = run;        // == NE
}

__global__ __launch_bounds__(256) void fill_elist(const int* __restrict__ ei,
                                                  int* __restrict__ cursor,
                                                  int2* __restrict__ se) {
    const int e = blockIdx.x * 256 + threadIdx.x;
    if (e < NE) {
        const int src = ei[e];
        const int pos = atomicAdd(&cursor[ei[NE + e]], 1);
        se[pos] = make_int2(src, e);
    }
}

// ---- GINE aggregation v2: wave-per-dst, float4 lanes, no barriers ----
//      z[dst] = (1+eps)h[dst] + sum_e relu(h[src_e] + eattr_e @ bond_w + bond_b)
__global__ __launch_bounds__(256) void gine_msg(const float* __restrict__ h,
                                                const float* __restrict__ eattr,
                                                const float* __restrict__ bond_w,
                                                const float* __restrict__ bond_b,
                                                const int2* __restrict__ se,
                                                const int* __restrict__ rowptr,
                                                const float* __restrict__ eps, int l,
                                                float* __restrict__ z) {
    const int dst = blockIdx.x * 4 + (threadIdx.x >> 6);
    const int lane = threadIdx.x & 63;
    const int c = lane * 4;
    float4 wb[FE];
    #pragma unroll
    for (int k = 0; k < FE; ++k) wb[k] = *(const float4*)(bond_w + k * H + c);
    const float4 bb = *(const float4*)(bond_b + c);
    const float sc = 1.0f + eps[l];
    const float4 hv = *(const float4*)(h + (size_t)dst * H + c);
    float4 acc;
    acc.x = sc * hv.x; acc.y = sc * hv.y; acc.z = sc * hv.z; acc.w = sc * hv.w;
    const int lo = rowptr[dst], hi = rowptr[dst + 1];
    for (int t = lo; t < hi; ++t) {
        const int2 pe = se[t];                       // {src, edge}
        const float4 hs = *(const float4*)(h + (size_t)pe.x * H + c);
        float4 ev = bb;
        #pragma unroll
        for (int k = 0; k < FE; ++k) {
            const float a = eattr[(size_t)pe.y * FE + k];   // wave-uniform, L1 broadcast
            ev.x += a * wb[k].x; ev.y += a * wb[k].y;
            ev.z += a * wb[k].z; ev.w += a * wb[k].w;
        }
        acc.x += fmaxf(hs.x + ev.x, 0.0f);
        acc.y += fmaxf(hs.y + ev.y, 0.0f);
        acc.z += fmaxf(hs.z + ev.z, 0.0f);
        acc.w += fmaxf(hs.w + ev.w, 0.0f);
    }
    *(float4*)(z + (size_t)dst * H + c) = acc;
}

// ---------------- split-bf16 3-pass MFMA GEMM, fused BN(+bias)+relu(+residual) ----------
// tile 128x128, BK=32, 256 thr = 4 waves (2x2), wave tile 64x64 (4x4 frags of 16x16x32)
// v2: prefetch next K-step's global loads under the MFMAs; XOR-swizzled 16B k-slots.
template <int KDIM, int EPI>
__global__ __launch_bounds__(256, 2) void gemm_mfma(
    const float* __restrict__ A,
    const unsigned short* __restrict__ BTh,
    const unsigned short* __restrict__ BTl,
    int Ncols,
    const float* __restrict__ bias, const float* __restrict__ bng,
    const float* __restrict__ bnb, const float* __restrict__ bnm,
    const float* __restrict__ bnv,
    float* __restrict__ C, const float* __restrict__ res)
{
    __shared__ __align__(16) unsigned short As_hi[128][40];
    __shared__ __align__(16) unsigned short As_lo[128][40];
    __shared__ __align__(16) unsigned short Bs_hi[128][40];
    __shared__ __align__(16) unsigned short Bs_lo[128][40];

    const int tid = threadIdx.x;
    const int nt = Ncols >> 7;
    // XCD-bijective swizzle (m204)
    const int nwg = gridDim.x, orig = blockIdx.x;
    const int q = nwg >> 3, r = nwg & 7;
    const int xcd = orig & 7, rk = orig >> 3;
    const int wg = (xcd < r ? xcd * (q + 1) : r * (q + 1) + (xcd - r) * q) + rk;
    const int m0 = (wg / nt) * 128;
    const int n0 = (wg % nt) * 128;

    const int wid = tid >> 6, lane = tid & 63;
    const int wm = wid >> 1, wn = wid & 1;
    const int lrow = lane & 15, lgrp = lane >> 4;
    const int sr = tid >> 3;                   // staging row 0..31
    const int sk = (tid & 7) * 4;              // global k-offset (ushorts)
    // swizzled LDS k-offset for staging writes (slot ^= row&3; same involution as reads)
    const int swk = 8 * ((((tid & 7) >> 1)) ^ (sr & 3)) + 4 * ((tid & 7) & 1);
    // swizzled slot for frag reads (row&3 == lrow&3 for all frags)
    const int slot8 = 8 * (lgrp ^ (lrow & 3));

    f32x4 acc[4][4];
    const f32x4 zero4 = {0.0f, 0.0f, 0.0f, 0.0f};
    #pragma unroll
    for (int i = 0; i < 4; ++i)
        #pragma unroll
        for (int j = 0; j < 4; ++j) acc[i][j] = zero4;

    float4 av[4]; ushort4 gh[4], gl[4];
    #define LOADK(K0)                                                              \
        _Pragma("unroll")                                                          \
        for (int i = 0; i < 4; ++i) {                                              \
            const int rr_ = sr + i * 32;                                           \
            av[i] = *(const float4*)(A + (size_t)(m0 + rr_) * KDIM + (K0) + sk);   \
            gh[i] = *(const ushort4*)(BTh + (size_t)(n0 + rr_) * KDIM + (K0) + sk);\
            gl[i] = *(const ushort4*)(BTl + (size_t)(n0 + rr_) * KDIM + (K0) + sk);\
        }

    LOADK(0);
    for (int k0 = 0; k0 < KDIM; k0 += 32) {
        __syncthreads();                       // prev iter's LDS reads done
        #pragma unroll
        for (int i = 0; i < 4; ++i) {
            const int rr = sr + i * 32;
            ushort4 hv, lv;
            hv.x = f2bf(av[i].x); lv.x = f2bf(av[i].x - bf2f(hv.x));
            hv.y = f2bf(av[i].y); lv.y = f2bf(av[i].y - bf2f(hv.y));
            hv.z = f2bf(av[i].z); lv.z = f2bf(av[i].z - bf2f(hv.z));
            hv.w = f2bf(av[i].w); lv.w = f2bf(av[i].w - bf2f(hv.w));
            *(ushort4*)&As_hi[rr][swk] = hv;
            *(ushort4*)&As_lo[rr][swk] = lv;
            *(ushort4*)&Bs_hi[rr][swk] = gh[i];
            *(ushort4*)&Bs_lo[rr][swk] = gl[i];
        }
        __syncthreads();
        if (k0 + 32 < KDIM) { LOADK(k0 + 32); }    // in flight under MFMAs
        s16x8 ah[4], al[4], bh[4], bl[4];
        #pragma unroll
        for (int mi = 0; mi < 4; ++mi) {
            const int ar = wm * 64 + mi * 16 + lrow;
            ah[mi] = *(const s16x8*)&As_hi[ar][slot8];
            al[mi] = *(const s16x8*)&As_lo[ar][slot8];
        }
        #pragma unroll
        for (int ni = 0; ni < 4; ++ni) {
            const int bc = wn * 64 + ni * 16 + lrow;
            bh[ni] = *(const s16x8*)&Bs_hi[bc][slot8];
            bl[ni] = *(const s16x8*)&Bs_lo[bc][slot8];
        }
        #pragma unroll
        for (int mi = 0; mi < 4; ++mi)
            #pragma unroll
            for (int ni = 0; ni < 4; ++ni) {
                acc[mi][ni] = __builtin_amdgcn_mfma_f32_16x16x32_bf16(ah[mi], bh[ni], acc[mi][ni], 0, 0, 0);
                acc[mi][ni] = __builtin_amdgcn_mfma_f32_16x16x32_bf16(al[mi], bh[ni], acc[mi][ni], 0, 0, 0);
                acc[mi][ni] = __builtin_amdgcn_mfma_f32_16x16x32_bf16(ah[mi], bl[ni], acc[mi][ni], 0, 0, 0);
            }
    }
    #undef LOADK

    float scl[4], shf[4];
    #pragma unroll
    for (int ni = 0; ni < 4; ++ni) {
        const int c = n0 + wn * 64 + ni * 16 + lrow;
        const float s = bng[c] * rsqrtf(bnv[c] + BN_EPS);
        scl[ni] = s;
        shf[ni] = s * (bias[c] - bnm[c]) + bnb[c];
    }
    #pragma unroll
    for (int mi = 0; mi < 4; ++mi)
        #pragma unroll
        for (int j = 0; j < 4; ++j) {
            const int row = m0 + wm * 64 + mi * 16 + lgrp * 4 + j;
            #pragma unroll
            for (int ni = 0; ni < 4; ++ni) {
                const int col = n0 + wn * 64 + ni * 16 + lrow;
                float v = fmaxf(scl[ni] * acc[mi][ni][j] + shf[ni], 0.0f);
                if (EPI == 1) v += res[(size_t)row * Ncols + col];
                C[(size_t)row * Ncols + col] = v;
            }
        }
}

// ---------------- pooling: mean + max per graph ----------------
__global__ __launch_bounds__(H) void pool_kernel(const float* __restrict__ h,
                                                 const int* __restrict__ batch,
                                                 float* __restrict__ p) {
    const int g = blockIdx.x;
    const int c = threadIdx.x;
    int lo, hi;
    {
        int a = 0, b = NA;
        while (a < b) { int mid = (a + b) >> 1; if (batch[mid] < g) a = mid + 1; else b = mid; }
        lo = a;
        b = NA;
        while (a < b) { int mid = (a + b) >> 1; if (batch[mid] < g + 1) a = mid + 1; else b = mid; }
        hi = a;
    }
    float sum = 0.0f, mx = -INFINITY;
    for (int n = lo; n < hi; ++n) {
        const float v = h[(size_t)n * H + c];
        sum += v;
        mx = fmaxf(mx, v);
    }
    const int cnt = hi - lo;
    const float mean = (cnt > 0) ? sum / (float)cnt : 0.0f;
    if (cnt == 0) mx = 0.0f;
    p[(size_t)g * H2 + c] = mean;
    p[(size_t)g * H2 + H + c] = mx;
}

// ---------------- classifier row-MLP ----------------
template <int Kdim, int Ncols>
__global__ __launch_bounds__(Ncols) void rowmlp(const float* __restrict__ A,
                                                const float* __restrict__ W,
                                                const float* __restrict__ bias,
                                                const float* __restrict__ bg,
                                                const float* __restrict__ bb,
                                                const float* __restrict__ bm,
                                                const float* __restrict__ bv,
                                                float* __restrict__ out) {
    __shared__ float as[Kdim];
    const int row = blockIdx.x;
    const int c = threadIdx.x;
    for (int k = c; k < Kdim; k += Ncols) as[k] = A[(size_t)row * Kdim + k];
    __syncthreads();
    float acc = 0.0f;
    #pragma unroll 8
    for (int k = 0; k < Kdim; ++k) acc += as[k] * W[k * Ncols + c];
    const float s = bg[c] * rsqrtf(bv[c] + BN_EPS);
    const float val = s * (acc + bias[c] - bm[c]) + bb[c];
    out[(size_t)row * Ncols + c] = fmaxf(val, 0.0f);
}

__global__ __launch_bounds__(64) void final_out(const float* __restrict__ q2,
                                                const float* __restrict__ w,
                                                const float* __restrict__ b,
                                                float* __restrict__ out) {
    const int g = blockIdx.x;
    const int lane = threadIdx.x;
    float acc = q2[(size_t)g * 128 + lane] * w[lane]
              + q2[(size_t)g * 128 + 64 + lane] * w[64 + lane];
    #pragma unroll
    for (int off = 32; off > 0; off >>= 1) acc += __shfl_down(acc, off);
    if (lane == 0) out[g] = acc + b[0];
}

// ---------------- launch ----------------
extern "C" void kernel_launch(void* const* d_in, const int* in_sizes, int n_in,
                              void* d_out, int out_size, void* d_ws, size_t ws_size,
                              hipStream_t stream) {
    const float* x      = (const float*)d_in[0];
    const int*   ei     = (const int*)d_in[1];
    const int*   batch  = (const int*)d_in[2];
    const float* eattr  = (const float*)d_in[3];
    const float* enc_w  = (const float*)d_in[4];
    const float* enc_b  = (const float*)d_in[5];
    const float* bond_w = (const float*)d_in[6];
    const float* bond_b = (const float*)d_in[7];
    const float* eps    = (const float*)d_in[8];
    const float* w1     = (const float*)d_in[9];
    const float* b1     = (const float*)d_in[10];
    const float* ibn_g  = (const float*)d_in[11];
    const float* ibn_b  = (const float*)d_in[12];
    const float* ibn_m  = (const float*)d_in[13];
    const float* ibn_v  = (const float*)d_in[14];
    const float* w2     = (const float*)d_in[15];
    const float* b2     = (const float*)d_in[16];
    const float* obn_g  = (const float*)d_in[17];
    const float* obn_b  = (const float*)d_in[18];
    const float* obn_m  = (const float*)d_in[19];
    const float* obn_v  = (const float*)d_in[20];
    const float* cw1    = (const float*)d_in[21];
    const float* cb1    = (const float*)d_in[22];
    const float* c1g    = (const float*)d_in[23];
    const float* c1b    = (const float*)d_in[24];
    const float* c1m    = (const float*)d_in[25];
    const float* c1v    = (const float*)d_in[26];
    const float* cw2    = (const float*)d_in[27];
    const float* cb2    = (const float*)d_in[28];
    const float* c2g    = (const float*)d_in[29];
    const float* c2b    = (const float*)d_in[30];
    const float* c2m    = (const float*)d_in[31];
    const float* c2v    = (const float*)d_in[32];
    const float* cw3    = (const float*)d_in[33];
    const float* cb3    = (const float*)d_in[34];
    float* out = (float*)d_out;

    // ---- workspace layout ----
    // [w splits: 4*NL*H*H2 ushort][deg NA][rowptr NA+1][cursor NA][se 2*NE][h][z][z1]
    const size_t WT = (size_t)NL * H * H2;
    const size_t wt_bytes  = 4 * WT * sizeof(unsigned short);        // 5.24 MB
    const size_t csr_words = (size_t)3 * NA + 1 + 2 * (size_t)NE + 63;
    const size_t csr_bytes = csr_words * 4;                          // ~3.7 MB
    const size_t hz_bytes  = (size_t)NA * H * 2 * 4;                 // 268 MB
    const size_t z1_bytes  = (size_t)NA * H2 * 4;                    // 268 MB
    const size_t need_full = wt_bytes + csr_bytes + hz_bytes + z1_bytes;

    float* buf;
    size_t buf_bytes;
    if (ws_size >= need_full) { buf = (float*)d_ws; buf_bytes = ws_size; }
    else if (g_buf)           { buf = g_buf;        buf_bytes = need_full; }
    else                      { buf = (float*)d_ws; buf_bytes = ws_size; }

    unsigned short* w1Th = (unsigned short*)buf;
    unsigned short* w1Tl = w1Th + WT;
    unsigned short* w2Th = w1Tl + WT;
    unsigned short* w2Tl = w2Th + WT;
    int*  deg    = (int*)(w2Tl + WT);
    int*  rowptr = deg + NA;
    int*  cursor = rowptr + NA + 1;
    int2* se     = (int2*)(cursor + NA);
    float* h   = (float*)((int*)(w2Tl + WT) + csr_words);
    float* z   = h + (size_t)NA * H;
    float* z1c = z + (size_t)NA * H;

    const size_t fixed_bytes = wt_bytes + csr_bytes + hz_bytes;
    const size_t avail_f = (buf_bytes > fixed_bytes) ? (buf_bytes - fixed_bytes) / 4 : 0;
    int CH = (int)(avail_f / H2);
    CH &= ~127;
    if (CH > NA) CH = NA;
    if (CH < 128) CH = 128;

    float* p  = z;                    // NG*H2 (z dead after last layer)
    float* q1 = p + (size_t)NG * H2;  // NG*H
    float* q2 = q1 + (size_t)NG * H;  // NG*(H/2)

    // ---- weight prep (transpose + hi/lo split), once per call ----
    for (int l = 0; l < NL; ++l) {
        prep_w<<<dim3(H / 32, H2 / 32), 256, 0, stream>>>(
            w1 + (size_t)l * H * H2, H, H2, w1Th + (size_t)l * H * H2, w1Tl + (size_t)l * H * H2);
        prep_w<<<dim3(H2 / 32, H / 32), 256, 0, stream>>>(
            w2 + (size_t)l * H2 * H, H2, H, w2Th + (size_t)l * H2 * H, w2Tl + (size_t)l * H2 * H);
    }

    // ---- CSR build (edges are layer-invariant) ----
    hipMemsetAsync(deg, 0, (size_t)NA * 4, stream);
    count_deg<<<NE / 256, 256, 0, stream>>>(ei, deg);
    scan_deg<<<1, 1024, 0, stream>>>(deg, rowptr, cursor);
    fill_elist<<<NE / 256, 256, 0, stream>>>(ei, cursor, se);

    encode_nodes<<<NA, H, 0, stream>>>(x, enc_w, enc_b, h);

    for (int l = 0; l < NL; ++l) {
        gine_msg<<<NA / 4, 256, 0, stream>>>(h, eattr, bond_w, bond_b, se, rowptr,
                                             eps, l, z);
        for (int r0 = 0; r0 < NA; r0 += CH) {
            const int CHc = (NA - r0 < CH) ? (NA - r0) : CH;
            gemm_mfma<H, 0><<<(CHc / 128) * (H2 / 128), 256, 0, stream>>>(
                z + (size_t)r0 * H, w1Th + (size_t)l * H * H2, w1Tl + (size_t)l * H * H2, H2,
                b1 + (size_t)l * H2, ibn_g + (size_t)l * H2, ibn_b + (size_t)l * H2,
                ibn_m + (size_t)l * H2, ibn_v + (size_t)l * H2, z1c, nullptr);
            gemm_mfma<H2, 1><<<(CHc / 128) * (H / 128), 256, 0, stream>>>(
                z1c, w2Th + (size_t)l * H2 * H, w2Tl + (size_t)l * H2 * H, H,
                b2 + (size_t)l * H, obn_g + (size_t)l * H, obn_b + (size_t)l * H,
                obn_m + (size_t)l * H, obn_v + (size_t)l * H,
                h + (size_t)r0 * H, h + (size_t)r0 * H);
        }
    }

    pool_kernel<<<NG, H, 0, stream>>>(h, batch, p);
    rowmlp<H2, H><<<NG, H, 0, stream>>>(p, cw1, cb1, c1g, c1b, c1m, c1v, q1);
    rowmlp<H, H / 2><<<NG, H / 2, 0, stream>>>(q1, cw2, cb2, c2g, c2b, c2m, c2v, q2);
    final_out<<<NG, 64, 0, stream>>>(q2, cw3, cb3, out);
}

// Round 7
// 2440.437 us; speedup vs baseline: 3.6585x; 1.1408x over previous
//
#include <hip/hip_runtime.h>
#include <math.h>

#define NA 131072   // atoms
#define NE 262144   // edges
#define NG 4096     // graphs
#define FN 30
#define FE 11
#define H  256
#define H2 512
#define NL 5
#define BN_EPS 1e-5f

typedef _Float16 f16x8 __attribute__((ext_vector_type(8)));
typedef _Float16 f16x4 __attribute__((ext_vector_type(4)));
typedef float f32x4 __attribute__((ext_vector_type(4)));

// ---- private fallback workspace, allocated ONCE at library load ----
static char* g_buf = nullptr;
__attribute__((constructor)) static void _alloc_private_ws() {
    void* p = nullptr;
    if (hipMalloc(&p, (size_t)512 * 1024 * 1024) == hipSuccess) g_buf = (char*)p;
}

// ---------------- weight prep: transpose to fp16 [N][K] ----------------
__global__ __launch_bounds__(256) void prep_w(const float* __restrict__ w, int K, int N,
                                              _Float16* __restrict__ hT) {
    __shared__ float t[32][33];
    const int k0 = blockIdx.x * 32, n0 = blockIdx.y * 32;
    const int tx = threadIdx.x & 31, ty = threadIdx.x >> 5;   // ty 0..7
    #pragma unroll
    for (int i = 0; i < 4; ++i)
        t[ty + i * 8][tx] = w[(size_t)(k0 + ty + i * 8) * N + n0 + tx];
    __syncthreads();
    #pragma unroll
    for (int i = 0; i < 4; ++i)
        hT[(size_t)(n0 + ty + i * 8) * K + k0 + tx] = (_Float16)t[tx][ty + i * 8];
}

// ---------------- node encoder: h fp32 + h16 fp16 ----------------
__global__ __launch_bounds__(H) void encode_nodes(const float* __restrict__ x,
                                                  const float* __restrict__ w,
                                                  const float* __restrict__ b,
                                                  float* __restrict__ h,
                                                  _Float16* __restrict__ h16) {
    __shared__ float xs[FN];
    const int row = blockIdx.x;
    const int c = threadIdx.x;
    if (c < FN) xs[c] = x[(size_t)row * FN + c];
    __syncthreads();
    float acc = b[c];
    #pragma unroll
    for (int k = 0; k < FN; ++k) acc += xs[k] * w[k * H + c];
    h[(size_t)row * H + c] = acc;
    h16[(size_t)row * H + c] = (_Float16)acc;
}

// ---------------- CSR build (once per call) ----------------
__global__ __launch_bounds__(256) void count_deg(const int* __restrict__ ei,
                                                 int* __restrict__ deg) {
    const int e = blockIdx.x * 256 + threadIdx.x;
    if (e < NE) atomicAdd(&deg[ei[NE + e]], 1);
}

__global__ __launch_bounds__(1024) void scan_deg(const int* __restrict__ deg,
                                                 int* __restrict__ rowptr,
                                                 int* __restrict__ cursor) {
    __shared__ int part[1024];
    const int t = threadIdx.x;
    const int base = t * 128;               // 1024*128 == NA
    int s = 0;
    #pragma unroll 8
    for (int i = 0; i < 128; ++i) s += deg[base + i];
    part[t] = s;
    __syncthreads();
    for (int off = 1; off < 1024; off <<= 1) {
        const int v = (t >= off) ? part[t - off] : 0;
        __syncthreads();
        part[t] += v;
        __syncthreads();
    }
    int run = (t == 0) ? 0 : part[t - 1];
    #pragma unroll 8
    for (int i = 0; i < 128; ++i) {
        rowptr[base + i] = run;
        cursor[base + i] = run;
        run += deg[base + i];
    }
    if (t == 1023) rowptr[NA] = run;        // == NE
}

__global__ __launch_bounds__(256) void fill_elist(const int* __restrict__ ei,
                                                  int* __restrict__ cursor,
                                                  int2* __restrict__ se) {
    const int e = blockIdx.x * 256 + threadIdx.x;
    if (e < NE) {
        const int src = ei[e];
        const int pos = atomicAdd(&cursor[ei[NE + e]], 1);
        se[pos] = make_int2(src, e);
    }
}

// ---- GINE aggregation: wave-per-dst, fp16 h in, fp16 z out ----
__global__ __launch_bounds__(256) void gine_msg(const _Float16* __restrict__ h16,
                                                const float* __restrict__ eattr,
                                                const float* __restrict__ bond_w,
                                                const float* __restrict__ bond_b,
                                                const int2* __restrict__ se,
                                                const int* __restrict__ rowptr,
                                                const float* __restrict__ eps, int l,
                                                _Float16* __restrict__ z) {
    const int dst = blockIdx.x * 4 + (threadIdx.x >> 6);
    const int lane = threadIdx.x & 63;
    const int c = lane * 4;
    float4 wb[FE];
    #pragma unroll
    for (int k = 0; k < FE; ++k) wb[k] = *(const float4*)(bond_w + k * H + c);
    const float4 bb = *(const float4*)(bond_b + c);
    const float sc = 1.0f + eps[l];
    const f16x4 hv = *(const f16x4*)(h16 + (size_t)dst * H + c);
    float4 acc;
    acc.x = sc * (float)hv.x; acc.y = sc * (float)hv.y;
    acc.z = sc * (float)hv.z; acc.w = sc * (float)hv.w;
    const int lo = rowptr[dst], hi = rowptr[dst + 1];
    for (int t = lo; t < hi; ++t) {
        const int2 pe = se[t];                       // {src, edge}
        const f16x4 hs = *(const f16x4*)(h16 + (size_t)pe.x * H + c);
        float4 ev = bb;
        #pragma unroll
        for (int k = 0; k < FE; ++k) {
            const float a = eattr[(size_t)pe.y * FE + k];   // wave-uniform
            ev.x += a * wb[k].x; ev.y += a * wb[k].y;
            ev.z += a * wb[k].z; ev.w += a * wb[k].w;
        }
        acc.x += fmaxf((float)hs.x + ev.x, 0.0f);
        acc.y += fmaxf((float)hs.y + ev.y, 0.0f);
        acc.z += fmaxf((float)hs.z + ev.z, 0.0f);
        acc.w += fmaxf((float)hs.w + ev.w, 0.0f);
    }
    f16x4 o;
    o.x = (_Float16)acc.x; o.y = (_Float16)acc.y;
    o.z = (_Float16)acc.z; o.w = (_Float16)acc.w;
    *(f16x4*)(z + (size_t)dst * H + c) = o;
}

// ---------------- fp16 MFMA GEMM, fused BN(+bias)+relu(+residual) ----------------
// C = epi(A[M,KDIM] @ B);  A fp16 [M][KDIM]; BT fp16 [Ncols][KDIM] (pre-transposed).
// tile 128x128, BK=32, 4 waves (2x2), wave tile 64x64. A via LDS (k-major, XOR-swizzled
// 16B slots, <=2-way banks); B frags direct from global (panel is L2-resident).
// EPI 0: C16 = relu(bn(acc+bias))      EPI 1: Cf = that + res (fp32), C16 = fp16 copy
template <int KDIM, int EPI>
__global__ __launch_bounds__(256, 3) void gemm_f16(
    const _Float16* __restrict__ A,
    const _Float16* __restrict__ BT,
    int Ncols,
    const float* __restrict__ bias, const float* __restrict__ bng,
    const float* __restrict__ bnb, const float* __restrict__ bnm,
    const float* __restrict__ bnv,
    _Float16* __restrict__ C16, float* __restrict__ Cf,
    const float* __restrict__ res)
{
    __shared__ f16x8 As[2][512];               // [buf][row*4 + slot], 16 KB total

    const int tid = threadIdx.x;
    const int nt = Ncols >> 7;
    // XCD-bijective swizzle (m204)
    const int nwg = gridDim.x, orig = blockIdx.x;
    const int q = nwg >> 3, r = nwg & 7;
    const int xcd = orig & 7, rk = orig >> 3;
    const int wg = (xcd < r ? xcd * (q + 1) : r * (q + 1) + (xcd - r) * q) + rk;
    const int m0 = (wg / nt) * 128;
    const int n0 = (wg % nt) * 128;

    const int wid = tid >> 6, lane = tid & 63;
    const int wm = wid >> 1, wn = wid & 1;
    const int lrow = lane & 15, lgrp = lane >> 4;
    const int r0s = tid >> 2;                  // staging row 0..63 (and +64)
    const int kq  = tid & 3;                   // staging 16B slot

    f32x4 acc[4][4];
    const f32x4 zero4 = {0.0f, 0.0f, 0.0f, 0.0f};
    #pragma unroll
    for (int i = 0; i < 4; ++i)
        #pragma unroll
        for (int j = 0; j < 4; ++j) acc[i][j] = zero4;

    f16x8 s0, s1;
    #define SLOAD(K0)                                                            \
        s0 = *(const f16x8*)(A + (size_t)(m0 + r0s) * KDIM + (K0) + kq * 8);     \
        s1 = *(const f16x8*)(A + (size_t)(m0 + r0s + 64) * KDIM + (K0) + kq * 8);
    #define SWRITE(CUR)                                                          \
        As[CUR][r0s * 4 + (kq ^ ((r0s >> 1) & 3))] = s0;                         \
        As[CUR][(r0s + 64) * 4 + (kq ^ (((r0s + 64) >> 1) & 3))] = s1;

    SLOAD(0);
    SWRITE(0);
    int cur = 0;
    for (int k0 = 0; k0 < KDIM; k0 += 32) {
        __syncthreads();                       // As[cur] ready; prior reads of As[cur^1] done
        if (k0 + 32 < KDIM) { SLOAD(k0 + 32); }
        f16x8 bf[4];
        #pragma unroll
        for (int ni = 0; ni < 4; ++ni) {
            const int bc = n0 + wn * 64 + ni * 16 + lrow;
            bf[ni] = *(const f16x8*)(BT + (size_t)bc * KDIM + k0 + lgrp * 8);
        }
        f16x8 af[4];
        #pragma unroll
        for (int mi = 0; mi < 4; ++mi) {
            const int ar = wm * 64 + mi * 16 + lrow;
            af[mi] = As[cur][ar * 4 + (lgrp ^ ((ar >> 1) & 3))];
        }
        #pragma unroll
        for (int mi = 0; mi < 4; ++mi)
            #pragma unroll
            for (int ni = 0; ni < 4; ++ni)
                acc[mi][ni] = __builtin_amdgcn_mfma_f32_16x16x32_f16(af[mi], bf[ni], acc[mi][ni], 0, 0, 0);
        if (k0 + 32 < KDIM) { SWRITE(cur ^ 1); }
        cur ^= 1;
    }
    #undef SLOAD
    #undef SWRITE

    float scl[4], shf[4];
    #pragma unroll
    for (int ni = 0; ni < 4; ++ni) {
        const int c = n0 + wn * 64 + ni * 16 + lrow;
        const float s = bng[c] * rsqrtf(bnv[c] + BN_EPS);
        scl[ni] = s;
        shf[ni] = s * (bias[c] - bnm[c]) + bnb[c];
    }
    #pragma unroll
    for (int mi = 0; mi < 4; ++mi)
        #pragma unroll
        for (int j = 0; j < 4; ++j) {
            const int row = m0 + wm * 64 + mi * 16 + lgrp * 4 + j;
            #pragma unroll
            for (int ni = 0; ni < 4; ++ni) {
                const int col = n0 + wn * 64 + ni * 16 + lrow;
                float v = fmaxf(scl[ni] * acc[mi][ni][j] + shf[ni], 0.0f);
                if (EPI == 1) {
                    v += res[(size_t)row * Ncols + col];
                    Cf[(size_t)row * Ncols + col] = v;
                }
                C16[(size_t)row * Ncols + col] = (_Float16)v;
            }
        }
}

// ---------------- pooling: mean + max per graph (h fp32) ----------------
__global__ __launch_bounds__(H) void pool_kernel(const float* __restrict__ h,
                                                 const int* __restrict__ batch,
                                                 float* __restrict__ p) {
    const int g = blockIdx.x;
    const int c = threadIdx.x;
    int lo, hi;
    {
        int a = 0, b = NA;
        while (a < b) { int mid = (a + b) >> 1; if (batch[mid] < g) a = mid + 1; else b = mid; }
        lo = a;
        b = NA;
        while (a < b) { int mid = (a + b) >> 1; if (batch[mid] < g + 1) a = mid + 1; else b = mid; }
        hi = a;
    }
    float sum = 0.0f, mx = -INFINITY;
    for (int n = lo; n < hi; ++n) {
        const float v = h[(size_t)n * H + c];
        sum += v;
        mx = fmaxf(mx, v);
    }
    const int cnt = hi - lo;
    const float mean = (cnt > 0) ? sum / (float)cnt : 0.0f;
    if (cnt == 0) mx = 0.0f;
    p[(size_t)g * H2 + c] = mean;
    p[(size_t)g * H2 + H + c] = mx;
}

// ---------------- classifier row-MLP ----------------
template <int Kdim, int Ncols>
__global__ __launch_bounds__(Ncols) void rowmlp(const float* __restrict__ A,
                                                const float* __restrict__ W,
                                                const float* __restrict__ bias,
                                                const float* __restrict__ bg,
                                                const float* __restrict__ bb,
                                                const float* __restrict__ bm,
                                                const float* __restrict__ bv,
                                                float* __restrict__ out) {
    __shared__ float as[Kdim];
    const int row = blockIdx.x;
    const int c = threadIdx.x;
    for (int k = c; k < Kdim; k += Ncols) as[k] = A[(size_t)row * Kdim + k];
    __syncthreads();
    float acc = 0.0f;
    #pragma unroll 8
    for (int k = 0; k < Kdim; ++k) acc += as[k] * W[k * Ncols + c];
    const float s = bg[c] * rsqrtf(bv[c] + BN_EPS);
    const float val = s * (acc + bias[c] - bm[c]) + bb[c];
    out[(size_t)row * Ncols + c] = fmaxf(val, 0.0f);
}

__global__ __launch_bounds__(64) void final_out(const float* __restrict__ q2,
                                                const float* __restrict__ w,
                                                const float* __restrict__ b,
                                                float* __restrict__ out) {
    const int g = blockIdx.x;
    const int lane = threadIdx.x;
    float acc = q2[(size_t)g * 128 + lane] * w[lane]
              + q2[(size_t)g * 128 + 64 + lane] * w[64 + lane];
    #pragma unroll
    for (int off = 32; off > 0; off >>= 1) acc += __shfl_down(acc, off);
    if (lane == 0) out[g] = acc + b[0];
}

// ---------------- launch ----------------
extern "C" void kernel_launch(void* const* d_in, const int* in_sizes, int n_in,
                              void* d_out, int out_size, void* d_ws, size_t ws_size,
                              hipStream_t stream) {
    const float* x      = (const float*)d_in[0];
    const int*   ei     = (const int*)d_in[1];
    const int*   batch  = (const int*)d_in[2];
    const float* eattr  = (const float*)d_in[3];
    const float* enc_w  = (const float*)d_in[4];
    const float* enc_b  = (const float*)d_in[5];
    const float* bond_w = (const float*)d_in[6];
    const float* bond_b = (const float*)d_in[7];
    const float* eps    = (const float*)d_in[8];
    const float* w1     = (const float*)d_in[9];
    const float* b1     = (const float*)d_in[10];
    const float* ibn_g  = (const float*)d_in[11];
    const float* ibn_b  = (const float*)d_in[12];
    const float* ibn_m  = (const float*)d_in[13];
    const float* ibn_v  = (const float*)d_in[14];
    const float* w2     = (const float*)d_in[15];
    const float* b2     = (const float*)d_in[16];
    const float* obn_g  = (const float*)d_in[17];
    const float* obn_b  = (const float*)d_in[18];
    const float* obn_m  = (const float*)d_in[19];
    const float* obn_v  = (const float*)d_in[20];
    const float* cw1    = (const float*)d_in[21];
    const float* cb1    = (const float*)d_in[22];
    const float* c1g    = (const float*)d_in[23];
    const float* c1b    = (const float*)d_in[24];
    const float* c1m    = (const float*)d_in[25];
    const float* c1v    = (const float*)d_in[26];
    const float* cw2    = (const float*)d_in[27];
    const float* cb2    = (const float*)d_in[28];
    const float* c2g    = (const float*)d_in[29];
    const float* c2b    = (const float*)d_in[30];
    const float* c2m    = (const float*)d_in[31];
    const float* c2v    = (const float*)d_in[32];
    const float* cw3    = (const float*)d_in[33];
    const float* cb3    = (const float*)d_in[34];
    float* out = (float*)d_out;

    // ---- workspace layout (bytes, all 16B-aligned) ----
    // [w1T fp16][w2T fp16][csr ints][h fp32][h16][z fp16][z1 fp16 chunk]
    const size_t WTE       = (size_t)NL * H * H2;            // elems per weight plane
    const size_t wt_bytes  = 2 * WTE * 2;                    // 2.6 MB
    const size_t csr_words = (size_t)3 * NA + 1 + 2 * (size_t)NE + 63;
    const size_t csr_bytes = csr_words * 4;
    const size_t h_bytes   = (size_t)NA * H * 4;             // 134 MB
    const size_t h16_bytes = (size_t)NA * H * 2;             // 67 MB
    const size_t z_bytes   = (size_t)NA * H * 2;             // 67 MB
    const size_t z1_bytes  = (size_t)NA * H2 * 2;            // 134 MB
    const size_t need_full = wt_bytes + csr_bytes + h_bytes + h16_bytes + z_bytes + z1_bytes;

    char* buf;
    size_t buf_bytes;
    if (ws_size >= need_full) { buf = (char*)d_ws; buf_bytes = ws_size; }
    else if (g_buf)           { buf = g_buf;       buf_bytes = (size_t)512 * 1024 * 1024; }
    else                      { buf = (char*)d_ws; buf_bytes = ws_size; }

    _Float16* w1T = (_Float16*)buf;
    _Float16* w2T = w1T + WTE;
    int*  deg    = (int*)(buf + wt_bytes);
    int*  rowptr = deg + NA;
    int*  cursor = rowptr + NA + 1;
    int2* se     = (int2*)(cursor + NA);
    float*    h   = (float*)(buf + wt_bytes + csr_bytes);
    _Float16* h16 = (_Float16*)((char*)h + h_bytes);
    _Float16* z   = (_Float16*)((char*)h16 + h16_bytes);
    _Float16* z1c = (_Float16*)((char*)z + z_bytes);

    const size_t fixed_bytes = wt_bytes + csr_bytes + h_bytes + h16_bytes + z_bytes;
    const size_t avail_rows = (buf_bytes > fixed_bytes) ? (buf_bytes - fixed_bytes) / ((size_t)H2 * 2) : 0;
    int CH = (int)avail_rows;
    CH &= ~127;
    if (CH > NA) CH = NA;
    if (CH < 128) CH = 128;

    float* p  = (float*)z;            // NG*H2 fp32 (z dead after last layer)
    float* q1 = p + (size_t)NG * H2;
    float* q2 = q1 + (size_t)NG * H;

    // ---- weight prep (transpose to fp16), once per call ----
    for (int l = 0; l < NL; ++l) {
        prep_w<<<dim3(H / 32, H2 / 32), 256, 0, stream>>>(
            w1 + (size_t)l * H * H2, H, H2, w1T + (size_t)l * H * H2);
        prep_w<<<dim3(H2 / 32, H / 32), 256, 0, stream>>>(
            w2 + (size_t)l * H2 * H, H2, H, w2T + (size_t)l * H2 * H);
    }

    // ---- CSR build (edges are layer-invariant) ----
    hipMemsetAsync(deg, 0, (size_t)NA * 4, stream);
    count_deg<<<NE / 256, 256, 0, stream>>>(ei, deg);
    scan_deg<<<1, 1024, 0, stream>>>(deg, rowptr, cursor);
    fill_elist<<<NE / 256, 256, 0, stream>>>(ei, cursor, se);

    encode_nodes<<<NA, H, 0, stream>>>(x, enc_w, enc_b, h, h16);

    for (int l = 0; l < NL; ++l) {
        gine_msg<<<NA / 4, 256, 0, stream>>>(h16, eattr, bond_w, bond_b, se, rowptr,
                                             eps, l, z);
        for (int r0 = 0; r0 < NA; r0 += CH) {
            const int CHc = (NA - r0 < CH) ? (NA - r0) : CH;
            gemm_f16<H, 0><<<(CHc / 128) * (H2 / 128), 256, 0, stream>>>(
                z + (size_t)r0 * H, w1T + (size_t)l * H * H2, H2,
                b1 + (size_t)l * H2, ibn_g + (size_t)l * H2, ibn_b + (size_t)l * H2,
                ibn_m + (size_t)l * H2, ibn_v + (size_t)l * H2,
                z1c, nullptr, nullptr);
            gemm_f16<H2, 1><<<(CHc / 128) * (H / 128), 256, 0, stream>>>(
                z1c, w2T + (size_t)l * H2 * H, H,
                b2 + (size_t)l * H, obn_g + (size_t)l * H, obn_b + (size_t)l * H,
                obn_m + (size_t)l * H, obn_v + (size_t)l * H,
                h16 + (size_t)r0 * H, h + (size_t)r0 * H, h + (size_t)r0 * H);
        }
    }

    pool_kernel<<<NG, H, 0, stream>>>(h, batch, p);
    rowmlp<H2, H><<<NG, H, 0, stream>>>(p, cw1, cb1, c1g, c1b, c1m, c1v, q1);
    rowmlp<H, H / 2><<<NG, H / 2, 0, stream>>>(q1, cw2, cb2, c2g, c2b, c2m, c2v, q2);
    final_out<<<NG, 64, 0, stream>>>(q2, cw3, cb3, out);
}

// Round 8
// 1938.788 us; speedup vs baseline: 4.6051x; 1.2587x over previous
//
#include <hip/hip_runtime.h>
#include <math.h>

#define NA 131072   // atoms
#define NE 262144   // edges
#define NG 4096     // graphs
#define FN 30
#define FE 11
#define H  256
#define H2 512
#define NL 5
#define BN_EPS 1e-5f

typedef _Float16 f16x8 __attribute__((ext_vector_type(8)));
typedef _Float16 f16x4 __attribute__((ext_vector_type(4)));
typedef float f32x4 __attribute__((ext_vector_type(4)));

// ---- private fallback workspace, allocated ONCE at library load ----
static char* g_buf = nullptr;
__attribute__((constructor)) static void _alloc_private_ws() {
    void* p = nullptr;
    if (hipMalloc(&p, (size_t)320 * 1024 * 1024) == hipSuccess) g_buf = (char*)p;
}

// ---------------- weight prep: transpose to fp16 [N][K] ----------------
__global__ __launch_bounds__(256) void prep_w(const float* __restrict__ w, int K, int N,
                                              _Float16* __restrict__ hT) {
    __shared__ float t[32][33];
    const int k0 = blockIdx.x * 32, n0 = blockIdx.y * 32;
    const int tx = threadIdx.x & 31, ty = threadIdx.x >> 5;   // ty 0..7
    #pragma unroll
    for (int i = 0; i < 4; ++i)
        t[ty + i * 8][tx] = w[(size_t)(k0 + ty + i * 8) * N + n0 + tx];
    __syncthreads();
    #pragma unroll
    for (int i = 0; i < 4; ++i)
        hT[(size_t)(n0 + ty + i * 8) * K + k0 + tx] = (_Float16)t[tx][ty + i * 8];
}

// ---------------- node encoder: 4 rows/block, fp16 out only ----------------
__global__ __launch_bounds__(256) void encode_nodes(const float* __restrict__ x,
                                                    const float* __restrict__ w,
                                                    const float* __restrict__ b,
                                                    _Float16* __restrict__ h16) {
    __shared__ float xs[4 * FN];
    const int t = threadIdx.x;
    const int blk = blockIdx.x;
    if (t < 4 * FN) xs[t] = x[(size_t)blk * 4 * FN + t];
    __syncthreads();
    const int rr = t >> 6;
    const int lane = t & 63;
    const int c = lane * 4;
    const float* xr = &xs[rr * FN];
    float4 acc = *(const float4*)(b + c);
    #pragma unroll
    for (int k = 0; k < FN; ++k) {
        const float a = xr[k];
        const float4 wv = *(const float4*)(w + (size_t)k * H + c);
        acc.x += a * wv.x; acc.y += a * wv.y; acc.z += a * wv.z; acc.w += a * wv.w;
    }
    f16x4 o;
    o.x = (_Float16)acc.x; o.y = (_Float16)acc.y;
    o.z = (_Float16)acc.z; o.w = (_Float16)acc.w;
    *(f16x4*)(h16 + (size_t)(blk * 4 + rr) * H + c) = o;
}

// ---------------- CSR build (once per call) ----------------
__global__ __launch_bounds__(256) void count_deg(const int* __restrict__ ei,
                                                 int* __restrict__ deg) {
    const int e = blockIdx.x * 256 + threadIdx.x;
    if (e < NE) atomicAdd(&deg[ei[NE + e]], 1);
}

__global__ __launch_bounds__(1024) void scan_deg(const int* __restrict__ deg,
                                                 int* __restrict__ rowptr,
                                                 int* __restrict__ cursor) {
    __shared__ int part[1024];
    const int t = threadIdx.x;
    const int base = t * 128;               // 1024*128 == NA
    int s = 0;
    #pragma unroll 8
    for (int i = 0; i < 128; ++i) s += deg[base + i];
    part[t] = s;
    __syncthreads();
    for (int off = 1; off < 1024; off <<= 1) {
        const int v = (t >= off) ? part[t - off] : 0;
        __syncthreads();
        part[t] += v;
        __syncthreads();
    }
    int run = (t == 0) ? 0 : part[t - 1];
    #pragma unroll 8
    for (int i = 0; i < 128; ++i) {
        rowptr[base + i] = run;
        cursor[base + i] = run;
        run += deg[base + i];
    }
    if (t == 1023) rowptr[NA] = run;        // == NE
}

__global__ __launch_bounds__(256) void fill_elist(const int* __restrict__ ei,
                                                  int* __restrict__ cursor,
                                                  int2* __restrict__ se) {
    const int e = blockIdx.x * 256 + threadIdx.x;
    if (e < NE) {
        const int src = ei[e];
        const int pos = atomicAdd(&cursor[ei[NE + e]], 1);
        se[pos] = make_int2(src, e);
    }
}

// ---- GINE aggregation: wave-per-dst, fp16 h in, fp16 z out ----
__global__ __launch_bounds__(256) void gine_msg(const _Float16* __restrict__ h16,
                                                const float* __restrict__ eattr,
                                                const float* __restrict__ bond_w,
                                                const float* __restrict__ bond_b,
                                                const int2* __restrict__ se,
                                                const int* __restrict__ rowptr,
                                                const float* __restrict__ eps, int l,
                                                _Float16* __restrict__ z) {
    const int dst = blockIdx.x * 4 + (threadIdx.x >> 6);
    const int lane = threadIdx.x & 63;
    const int c = lane * 4;
    float4 wb[FE];
    #pragma unroll
    for (int k = 0; k < FE; ++k) wb[k] = *(const float4*)(bond_w + k * H + c);
    const float4 bb = *(const float4*)(bond_b + c);
    const float sc = 1.0f + eps[l];
    const f16x4 hv = *(const f16x4*)(h16 + (size_t)dst * H + c);
    float4 acc;
    acc.x = sc * (float)hv.x; acc.y = sc * (float)hv.y;
    acc.z = sc * (float)hv.z; acc.w = sc * (float)hv.w;
    const int lo = rowptr[dst], hi = rowptr[dst + 1];
    for (int t = lo; t < hi; ++t) {
        const int2 pe = se[t];                       // {src, edge}
        const f16x4 hs = *(const f16x4*)(h16 + (size_t)pe.x * H + c);
        float4 ev = bb;
        #pragma unroll
        for (int k = 0; k < FE; ++k) {
            const float a = eattr[(size_t)pe.y * FE + k];   // wave-uniform
            ev.x += a * wb[k].x; ev.y += a * wb[k].y;
            ev.z += a * wb[k].z; ev.w += a * wb[k].w;
        }
        acc.x += fmaxf((float)hs.x + ev.x, 0.0f);
        acc.y += fmaxf((float)hs.y + ev.y, 0.0f);
        acc.z += fmaxf((float)hs.z + ev.z, 0.0f);
        acc.w += fmaxf((float)hs.w + ev.w, 0.0f);
    }
    f16x4 o;
    o.x = (_Float16)acc.x; o.y = (_Float16)acc.y;
    o.z = (_Float16)acc.z; o.w = (_Float16)acc.w;
    *(f16x4*)(z + (size_t)dst * H + c) = o;
}

// ---------------- fp16 MFMA GEMM v3: A AND B through double-buffered LDS ------------
// C16 = epi(A[M,KDIM] @ B); BT fp16 [Ncols][KDIM]. tile 128x128, BK=32, 4 waves (2x2).
// One barrier per K-step; next step's global loads issued right after it (fly under MFMAs).
// XOR-swizzled 16B slots: slot = kq ^ ((row>>1)&3)  ->  <=2-way banks on write & read.
// EPI 0: C16 = relu(bn(acc+bias))    EPI 1: C16 = that + res (fp16; res may alias C16)
template <int KDIM, int EPI>
__global__ __launch_bounds__(256, 3) void gemm_f16(
    const _Float16* __restrict__ A,
    const _Float16* __restrict__ BT,
    int Ncols,
    const float* __restrict__ bias, const float* __restrict__ bng,
    const float* __restrict__ bnb, const float* __restrict__ bnm,
    const float* __restrict__ bnv,
    _Float16* __restrict__ C16, const _Float16* __restrict__ res)
{
    __shared__ f16x8 As[2][512];               // [buf][row*4 + slot]
    __shared__ f16x8 Bs[2][512];

    const int tid = threadIdx.x;
    const int nt = Ncols >> 7;
    // XCD-bijective swizzle (m204)
    const int nwg = gridDim.x, orig = blockIdx.x;
    const int q = nwg >> 3, r = nwg & 7;
    const int xcd = orig & 7, rk = orig >> 3;
    const int wg = (xcd < r ? xcd * (q + 1) : r * (q + 1) + (xcd - r) * q) + rk;
    const int m0 = (wg / nt) * 128;
    const int n0 = (wg % nt) * 128;

    const int wid = tid >> 6, lane = tid & 63;
    const int wm = wid >> 1, wn = wid & 1;
    const int lrow = lane & 15, lgrp = lane >> 4;
    const int r0s = tid >> 2;                  // staging row 0..63 (and +64)
    const int kq  = tid & 3;                   // staging 16B slot
    const int sw0 = kq ^ ((r0s >> 1) & 3);
    const int sw1 = kq ^ (((r0s + 64) >> 1) & 3);

    f32x4 acc[4][4];
    const f32x4 zero4 = {0.0f, 0.0f, 0.0f, 0.0f};
    #pragma unroll
    for (int i = 0; i < 4; ++i)
        #pragma unroll
        for (int j = 0; j < 4; ++j) acc[i][j] = zero4;

    f16x8 a0, a1, b0, b1;
    #define SLOAD(K0)                                                             \
        a0 = *(const f16x8*)(A  + (size_t)(m0 + r0s) * KDIM + (K0) + kq * 8);     \
        a1 = *(const f16x8*)(A  + (size_t)(m0 + r0s + 64) * KDIM + (K0) + kq * 8);\
        b0 = *(const f16x8*)(BT + (size_t)(n0 + r0s) * KDIM + (K0) + kq * 8);     \
        b1 = *(const f16x8*)(BT + (size_t)(n0 + r0s + 64) * KDIM + (K0) + kq * 8);
    #define SWRITE(CUR)                                                           \
        As[CUR][r0s * 4 + sw0] = a0;  As[CUR][(r0s + 64) * 4 + sw1] = a1;         \
        Bs[CUR][r0s * 4 + sw0] = b0;  Bs[CUR][(r0s + 64) * 4 + sw1] = b1;

    SLOAD(0);
    int cur = 0;
    for (int k0 = 0; k0 < KDIM; k0 += 32) {
        SWRITE(cur);
        __syncthreads();                       // buf ready; also fences reads 2 iters back
        if (k0 + 32 < KDIM) { SLOAD(k0 + 32); }    // lands under the MFMAs below
        f16x8 af[4], bf[4];
        #pragma unroll
        for (int mi = 0; mi < 4; ++mi) {
            const int ar = wm * 64 + mi * 16 + lrow;
            af[mi] = As[cur][ar * 4 + (lgrp ^ ((ar >> 1) & 3))];
        }
        #pragma unroll
        for (int ni = 0; ni < 4; ++ni) {
            const int br = wn * 64 + ni * 16 + lrow;
            bf[ni] = Bs[cur][br * 4 + (lgrp ^ ((br >> 1) & 3))];
        }
        #pragma unroll
        for (int mi = 0; mi < 4; ++mi)
            #pragma unroll
            for (int ni = 0; ni < 4; ++ni)
                acc[mi][ni] = __builtin_amdgcn_mfma_f32_16x16x32_f16(af[mi], bf[ni], acc[mi][ni], 0, 0, 0);
        cur ^= 1;
    }
    #undef SLOAD
    #undef SWRITE

    float scl[4], shf[4];
    #pragma unroll
    for (int ni = 0; ni < 4; ++ni) {
        const int c = n0 + wn * 64 + ni * 16 + lrow;
        const float s = bng[c] * rsqrtf(bnv[c] + BN_EPS);
        scl[ni] = s;
        shf[ni] = s * (bias[c] - bnm[c]) + bnb[c];
    }
    #pragma unroll
    for (int mi = 0; mi < 4; ++mi)
        #pragma unroll
        for (int j = 0; j < 4; ++j) {
            const int row = m0 + wm * 64 + mi * 16 + lgrp * 4 + j;
            #pragma unroll
            for (int ni = 0; ni < 4; ++ni) {
                const int col = n0 + wn * 64 + ni * 16 + lrow;
                float v = fmaxf(scl[ni] * acc[mi][ni][j] + shf[ni], 0.0f);
                if (EPI == 1) v += (float)res[(size_t)row * Ncols + col];
                C16[(size_t)row * Ncols + col] = (_Float16)v;
            }
        }
}

// ---------------- pooling: mean + max per graph (fp16 h, fp32 accum) ----------------
__global__ __launch_bounds__(H) void pool_kernel(const _Float16* __restrict__ h16,
                                                 const int* __restrict__ batch,
                                                 float* __restrict__ p) {
    const int g = blockIdx.x;
    const int c = threadIdx.x;
    int lo, hi;
    {
        int a = 0, b = NA;
        while (a < b) { int mid = (a + b) >> 1; if (batch[mid] < g) a = mid + 1; else b = mid; }
        lo = a;
        b = NA;
        while (a < b) { int mid = (a + b) >> 1; if (batch[mid] < g + 1) a = mid + 1; else b = mid; }
        hi = a;
    }
    float sum = 0.0f, mx = -INFINITY;
    for (int n = lo; n < hi; ++n) {
        const float v = (float)h16[(size_t)n * H + c];
        sum += v;
        mx = fmaxf(mx, v);
    }
    const int cnt = hi - lo;
    const float mean = (cnt > 0) ? sum / (float)cnt : 0.0f;
    if (cnt == 0) mx = 0.0f;
    p[(size_t)g * H2 + c] = mean;
    p[(size_t)g * H2 + H + c] = mx;
}

// ---------------- classifier row-MLP ----------------
template <int Kdim, int Ncols>
__global__ __launch_bounds__(Ncols) void rowmlp(const float* __restrict__ A,
                                                const float* __restrict__ W,
                                                const float* __restrict__ bias,
                                                const float* __restrict__ bg,
                                                const float* __restrict__ bb,
                                                const float* __restrict__ bm,
                                                const float* __restrict__ bv,
                                                float* __restrict__ out) {
    __shared__ float as[Kdim];
    const int row = blockIdx.x;
    const int c = threadIdx.x;
    for (int k = c; k < Kdim; k += Ncols) as[k] = A[(size_t)row * Kdim + k];
    __syncthreads();
    float acc = 0.0f;
    #pragma unroll 8
    for (int k = 0; k < Kdim; ++k) acc += as[k] * W[k * Ncols + c];
    const float s = bg[c] * rsqrtf(bv[c] + BN_EPS);
    const float val = s * (acc + bias[c] - bm[c]) + bb[c];
    out[(size_t)row * Ncols + c] = fmaxf(val, 0.0f);
}

__global__ __launch_bounds__(64) void final_out(const float* __restrict__ q2,
                                                const float* __restrict__ w,
                                                const float* __restrict__ b,
                                                float* __restrict__ out) {
    const int g = blockIdx.x;
    const int lane = threadIdx.x;
    float acc = q2[(size_t)g * 128 + lane] * w[lane]
              + q2[(size_t)g * 128 + 64 + lane] * w[64 + lane];
    #pragma unroll
    for (int off = 32; off > 0; off >>= 1) acc += __shfl_down(acc, off);
    if (lane == 0) out[g] = acc + b[0];
}

// ---------------- launch ----------------
extern "C" void kernel_launch(void* const* d_in, const int* in_sizes, int n_in,
                              void* d_out, int out_size, void* d_ws, size_t ws_size,
                              hipStream_t stream) {
    const float* x      = (const float*)d_in[0];
    const int*   ei     = (const int*)d_in[1];
    const int*   batch  = (const int*)d_in[2];
    const float* eattr  = (const float*)d_in[3];
    const float* enc_w  = (const float*)d_in[4];
    const float* enc_b  = (const float*)d_in[5];
    const float* bond_w = (const float*)d_in[6];
    const float* bond_b = (const float*)d_in[7];
    const float* eps    = (const float*)d_in[8];
    const float* w1     = (const float*)d_in[9];
    const float* b1     = (const float*)d_in[10];
    const float* ibn_g  = (const float*)d_in[11];
    const float* ibn_b  = (const float*)d_in[12];
    const float* ibn_m  = (const float*)d_in[13];
    const float* ibn_v  = (const float*)d_in[14];
    const float* w2     = (const float*)d_in[15];
    const float* b2     = (const float*)d_in[16];
    const float* obn_g  = (const float*)d_in[17];
    const float* obn_b  = (const float*)d_in[18];
    const float* obn_m  = (const float*)d_in[19];
    const float* obn_v  = (const float*)d_in[20];
    const float* cw1    = (const float*)d_in[21];
    const float* cb1    = (const float*)d_in[22];
    const float* c1g    = (const float*)d_in[23];
    const float* c1b    = (const float*)d_in[24];
    const float* c1m    = (const float*)d_in[25];
    const float* c1v    = (const float*)d_in[26];
    const float* cw2    = (const float*)d_in[27];
    const float* cb2    = (const float*)d_in[28];
    const float* c2g    = (const float*)d_in[29];
    const float* c2b    = (const float*)d_in[30];
    const float* c2m    = (const float*)d_in[31];
    const float* c2v    = (const float*)d_in[32];
    const float* cw3    = (const float*)d_in[33];
    const float* cb3    = (const float*)d_in[34];
    float* out = (float*)d_out;

    // ---- workspace layout (fp16 datapath) ----
    // [w1T][w2T fp16][csr ints][h16][z fp16][z1 fp16 chunk]   (~275 MB full)
    const size_t WTE       = (size_t)NL * H * H2;
    const size_t wt_bytes  = 2 * WTE * 2;
    const size_t csr_words = (size_t)3 * NA + 1 + 2 * (size_t)NE + 63;
    const size_t csr_bytes = csr_words * 4;
    const size_t h16_bytes = (size_t)NA * H * 2;             // 67 MB
    const size_t z_bytes   = (size_t)NA * H * 2;             // 67 MB
    const size_t z1_bytes  = (size_t)NA * H2 * 2;            // 134 MB
    const size_t need_full = wt_bytes + csr_bytes + h16_bytes + z_bytes + z1_bytes;

    char* buf;
    size_t buf_bytes;
    if (ws_size >= need_full) { buf = (char*)d_ws; buf_bytes = ws_size; }
    else if (g_buf)           { buf = g_buf;       buf_bytes = (size_t)320 * 1024 * 1024; }
    else                      { buf = (char*)d_ws; buf_bytes = ws_size; }

    _Float16* w1T = (_Float16*)buf;
    _Float16* w2T = w1T + WTE;
    int*  deg    = (int*)(buf + wt_bytes);
    int*  rowptr = deg + NA;
    int*  cursor = rowptr + NA + 1;
    int2* se     = (int2*)(cursor + NA);
    _Float16* h16 = (_Float16*)(buf + wt_bytes + csr_bytes);
    _Float16* z   = (_Float16*)((char*)h16 + h16_bytes);
    _Float16* z1c = (_Float16*)((char*)z + z_bytes);

    const size_t fixed_bytes = wt_bytes + csr_bytes + h16_bytes + z_bytes;
    const size_t avail_rows = (buf_bytes > fixed_bytes) ? (buf_bytes - fixed_bytes) / ((size_t)H2 * 2) : 0;
    int CH = (int)avail_rows;
    CH &= ~127;
    if (CH > NA) CH = NA;
    if (CH < 128) CH = 128;

    float* p  = (float*)z;            // NG*H2 fp32 (z dead after last layer; 8MB < 67MB)
    float* q1 = p + (size_t)NG * H2;
    float* q2 = q1 + (size_t)NG * H;

    // ---- weight prep (transpose to fp16), once per call ----
    for (int l = 0; l < NL; ++l) {
        prep_w<<<dim3(H / 32, H2 / 32), 256, 0, stream>>>(
            w1 + (size_t)l * H * H2, H, H2, w1T + (size_t)l * H * H2);
        prep_w<<<dim3(H2 / 32, H / 32), 256, 0, stream>>>(
            w2 + (size_t)l * H2 * H, H2, H, w2T + (size_t)l * H2 * H);
    }

    // ---- CSR build (edges are layer-invariant) ----
    hipMemsetAsync(deg, 0, (size_t)NA * 4, stream);
    count_deg<<<NE / 256, 256, 0, stream>>>(ei, deg);
    scan_deg<<<1, 1024, 0, stream>>>(deg, rowptr, cursor);
    fill_elist<<<NE / 256, 256, 0, stream>>>(ei, cursor, se);

    encode_nodes<<<NA / 4, 256, 0, stream>>>(x, enc_w, enc_b, h16);

    for (int l = 0; l < NL; ++l) {
        gine_msg<<<NA / 4, 256, 0, stream>>>(h16, eattr, bond_w, bond_b, se, rowptr,
                                             eps, l, z);
        for (int r0 = 0; r0 < NA; r0 += CH) {
            const int CHc = (NA - r0 < CH) ? (NA - r0) : CH;
            gemm_f16<H, 0><<<(CHc / 128) * (H2 / 128), 256, 0, stream>>>(
                z + (size_t)r0 * H, w1T + (size_t)l * H * H2, H2,
                b1 + (size_t)l * H2, ibn_g + (size_t)l * H2, ibn_b + (size_t)l * H2,
                ibn_m + (size_t)l * H2, ibn_v + (size_t)l * H2,
                z1c, nullptr);
            gemm_f16<H2, 1><<<(CHc / 128) * (H / 128), 256, 0, stream>>>(
                z1c, w2T + (size_t)l * H2 * H, H,
                b2 + (size_t)l * H, obn_g + (size_t)l * H, obn_b + (size_t)l * H,
                obn_m + (size_t)l * H, obn_v + (size_t)l * H,
                h16 + (size_t)r0 * H, h16 + (size_t)r0 * H);
        }
    }

    pool_kernel<<<NG, H, 0, stream>>>(h16, batch, p);
    rowmlp<H2, H><<<NG, H, 0, stream>>>(p, cw1, cb1, c1g, c1b, c1m, c1v, q1);
    rowmlp<H, H / 2><<<NG, H / 2, 0, stream>>>(q1, cw2, cb2, c2g, c2b, c2m, c2v, q2);
    final_out<<<NG, 64, 0, stream>>>(q2, cw3, cb3, out);
}